// Round 5
// baseline (724.351 us; speedup 1.0000x reference)
//
#include <hip/hip_runtime.h>

// ---------------------------------------------------------------------------
// PanguProMoE decoder layer, MI355X (gfx950).
// Precision: qkv GEMM + attention in split-f16 ("f16x2": x = hi + lo/1024,
// 3 MFMAs/tile). Router logits via exact linear path (see router_linear).
// Post-router MoE in plain f16. RoPE angles in double.
// R5: (a) chunked-KV attention (<=16 kv-tiles/block, 1280 uniform blocks,
// 3 blocks/CU) + fp32 partial combine -- removes the long-block tail that
// capped occupancy at 12.5%; (b) 2-phase double-buffered GEMMs (stage next
// K-tile during MFMA, one barrier/K-step); qkv GEMM 3 blocks/CU.
// ---------------------------------------------------------------------------

typedef _Float16 half_t;
typedef _Float16 half8 __attribute__((ext_vector_type(8)));
typedef float    f32x4 __attribute__((ext_vector_type(4)));
typedef float    floatx4 __attribute__((ext_vector_type(4)));

#define T_TOK 2048
#define HIDN  2048
#define NH    16
#define NKVH  4
#define HD    128
#define QKV_N 3072
#define NEXP  8

#define MFMA16(a,b,c) __builtin_amdgcn_mfma_f32_16x16x32_f16(a,b,c,0,0,0)

__device__ __forceinline__ void gload_lds16(const half_t* g, half_t* l) {
    __builtin_amdgcn_global_load_lds(
        (const __attribute__((address_space(1))) void*)g,
        (__attribute__((address_space(3))) void*)l, 16, 0, 0);
}

// ---------------------------------------------------------------------------
// rmsnorm over HIDN cols, write split f16 (lo optional)
// ---------------------------------------------------------------------------
__global__ __launch_bounds__(256)
void rmsnorm_split_k(const float* __restrict__ x, const float* __restrict__ w,
                     half_t* __restrict__ hi, half_t* __restrict__ lo)
{
    const int row = blockIdx.x, tid = threadIdx.x;
    const float* xr = x + (size_t)row * HIDN;
    floatx4 v0 = *(const floatx4*)(xr + tid * 8);
    floatx4 v1 = *(const floatx4*)(xr + tid * 8 + 4);
    float ss = v0[0]*v0[0] + v0[1]*v0[1] + v0[2]*v0[2] + v0[3]*v0[3]
             + v1[0]*v1[0] + v1[1]*v1[1] + v1[2]*v1[2] + v1[3]*v1[3];
    for (int o = 32; o; o >>= 1) ss += __shfl_down(ss, o);
    __shared__ float red[4];
    if ((tid & 63) == 0) red[tid >> 6] = ss;
    __syncthreads();
    ss = red[0] + red[1] + red[2] + red[3];
    float rs = rsqrtf(ss * (1.0f / HIDN) + 1e-6f);
    floatx4 w0 = *(const floatx4*)(w + tid * 8);
    floatx4 w1 = *(const floatx4*)(w + tid * 8 + 4);
    float vv[8] = { v0[0]*w0[0], v0[1]*w0[1], v0[2]*w0[2], v0[3]*w0[3],
                    v1[0]*w1[0], v1[1]*w1[1], v1[2]*w1[2], v1[3]*w1[3] };
    half8 hv, lv;
#pragma unroll
    for (int j = 0; j < 8; ++j) {
        float o = vv[j] * rs;
        half_t h = (half_t)o;
        hv[j] = h;
        lv[j] = (half_t)((o - (float)h) * 1024.0f);
    }
    *(half8*)(hi + (size_t)row * HIDN + tid * 8) = hv;
    if (lo) *(half8*)(lo + (size_t)row * HIDN + tid * 8) = lv;
}

// ---------------------------------------------------------------------------
// Transpose fp32 -> split f16: dst[n][k] = src[k][n]. 32x32 tile.
// ---------------------------------------------------------------------------
__global__ __launch_bounds__(256)
void transpose_split2(const float* __restrict__ src, half_t* __restrict__ dh,
                      half_t* __restrict__ dl, int sstride, int dstride)
{
    __shared__ float tile[32][36];
    const int n0 = blockIdx.x * 32, k0 = blockIdx.y * 32;
    const int tid = threadIdx.x;
    {
        int r = tid >> 3, c = (tid & 7) * 4;
        *(floatx4*)&tile[r][c] =
            *(const floatx4*)(src + (size_t)(k0 + r) * sstride + n0 + c);
    }
    __syncthreads();
    int n = tid & 31, g = tid >> 5, gg = g & 3;
    half8 hv;
    if (g < 4) {
#pragma unroll
        for (int j = 0; j < 8; ++j) hv[j] = (half_t)tile[gg * 8 + j][n];
        *(half8*)(dh + (size_t)(n0 + n) * dstride + k0 + gg * 8) = hv;
    } else {
#pragma unroll
        for (int j = 0; j < 8; ++j) {
            float v = tile[gg * 8 + j][n];
            half_t h = (half_t)v;
            hv[j] = (half_t)((v - (float)h) * 1024.0f);
        }
        *(half8*)(dl + (size_t)(n0 + n) * dstride + k0 + gg * 8) = hv;
    }
}

// ---------------------------------------------------------------------------
// Transpose fp32 -> single f16: dst[n][k] = src[k][n]. 32(k)x64(n) tile.
// ---------------------------------------------------------------------------
__global__ __launch_bounds__(256)
void transpose_f16(const float* __restrict__ src, half_t* __restrict__ dh,
                   int sstride, int dstride)
{
    __shared__ float tile[32][68];
    const int n0 = blockIdx.x * 64, k0 = blockIdx.y * 32;
    const int tid = threadIdx.x;
    {
        int r = tid >> 3, c = (tid & 7) * 4;
        const float* s = src + (size_t)(k0 + r) * sstride + n0;
        *(floatx4*)&tile[r][c]      = *(const floatx4*)(s + c);
        *(floatx4*)&tile[r][c + 32] = *(const floatx4*)(s + c + 32);
    }
    __syncthreads();
    int n = tid & 63, g = tid >> 6;
    half8 hv;
#pragma unroll
    for (int j = 0; j < 8; ++j) hv[j] = (half_t)tile[g * 8 + j][n];
    *(half8*)(dh + (size_t)(n0 + n) * dstride + k0 + g * 8) = hv;
}

// ---------------------------------------------------------------------------
// Batched W13 transpose: W13t[n][k] (n<10240, k<2048), f16.
// ---------------------------------------------------------------------------
__global__ __launch_bounds__(256)
void w13_transpose(const float* __restrict__ sw1, const float* __restrict__ w1,
                   const float* __restrict__ sw3, const float* __restrict__ w3,
                   half_t* __restrict__ dst)
{
    __shared__ float tile[32][68];
    const int n0 = blockIdx.x * 64, k0 = blockIdx.y * 32;
    const int tid = threadIdx.x;
    const float* base;
    int stride;
    if (n0 < 1024)      { base = sw1 + n0; stride = 1024; }
    else if (n0 < 5120) { int e = (n0 - 1024) >> 9;
                          base = w1 + (size_t)e * HIDN * 512 + ((n0 - 1024) & 511);
                          stride = 512; }
    else if (n0 < 6144) { base = sw3 + (n0 - 5120); stride = 1024; }
    else                { int e = (n0 - 6144) >> 9;
                          base = w3 + (size_t)e * HIDN * 512 + ((n0 - 6144) & 511);
                          stride = 512; }
    {
        int r = tid >> 3, c = (tid & 7) * 4;
        const float* s = base + (size_t)(k0 + r) * stride;
        *(floatx4*)&tile[r][c]      = *(const floatx4*)(s + c);
        *(floatx4*)&tile[r][c + 32] = *(const floatx4*)(s + c + 32);
    }
    __syncthreads();
    int n = tid & 63, g = tid >> 6;
    half8 hv;
#pragma unroll
    for (int j = 0; j < 8; ++j) hv[j] = (half_t)tile[g * 8 + j][n];
    *(half8*)(dst + (size_t)(n0 + n) * HIDN + k0 + g * 8) = hv;
}

// ---------------------------------------------------------------------------
// Batched W2 transpose: W2t[n][k] (n<2048, k<5120), f16, dstride 5120.
// ---------------------------------------------------------------------------
__global__ __launch_bounds__(256)
void w2_transpose(const float* __restrict__ sw2, const float* __restrict__ w2,
                  half_t* __restrict__ dst)
{
    __shared__ float tile[32][68];
    const int n0 = blockIdx.x * 64, k0 = blockIdx.y * 32;
    const int tid = threadIdx.x;
    {
        int r = tid >> 3, c = (tid & 7) * 4;
        int k = k0 + r;
        const float* s;
        if (k < 1024) s = sw2 + (size_t)k * HIDN + n0;
        else {
            int e = (k - 1024) >> 9, kk = (k - 1024) & 511;
            s = w2 + ((size_t)e * 512 + kk) * HIDN + n0;
        }
        *(floatx4*)&tile[r][c]      = *(const floatx4*)(s + c);
        *(floatx4*)&tile[r][c + 32] = *(const floatx4*)(s + c + 32);
    }
    __syncthreads();
    int n = tid & 63, g = tid >> 6;
    half8 hv;
#pragma unroll
    for (int j = 0; j < 8; ++j) hv[j] = (half_t)tile[g * 8 + j][n];
    *(half8*)(dst + (size_t)(n0 + n) * 5120 + k0 + g * 8) = hv;
}

// ---------------------------------------------------------------------------
// ow_u[k][e] = sum_c o_w[k][c] * ln2w[c] * rw[c][e]   (fp32, 2048x8)
// ---------------------------------------------------------------------------
__global__ __launch_bounds__(256)
void owu_kernel(const float* __restrict__ ow, const float* __restrict__ ln2w,
                const float* __restrict__ rw, float* __restrict__ owu)
{
    const int k = blockIdx.x * 4 + (threadIdx.x >> 6);
    const int lane = threadIdx.x & 63;
    float acc[NEXP] = {};
    const float* row = ow + (size_t)k * HIDN;
#pragma unroll
    for (int j = 0; j < 8; ++j) {
        int c = j * 256 + lane * 4;
        floatx4 ov = *(const floatx4*)(row + c);
        floatx4 lw = *(const floatx4*)(ln2w + c);
#pragma unroll
        for (int i = 0; i < 4; ++i) {
            float s = ov[i] * lw[i];
            const float* rwc = rw + (size_t)(c + i) * NEXP;
#pragma unroll
            for (int e = 0; e < NEXP; ++e) acc[e] += s * rwc[e];
        }
    }
#pragma unroll
    for (int e = 0; e < NEXP; ++e)
        for (int o = 32; o; o >>= 1) acc[e] += __shfl_down(acc[e], o);
    if (lane == 0) {
#pragma unroll
        for (int e = 0; e < NEXP; ++e) owu[(size_t)k * NEXP + e] = acc[e];
    }
}

// ---------------------------------------------------------------------------
// GEMM: C[M][N] = A[M][K] @ Bt[N][K]^T (+bias)(+res). f16 in, fp32 acc.
// SPLIT: (hi, lo*1024) pairs, 3 MFMAs/tile. BM x 128 tile, BK=32, 4 waves.
// 2-phase double-buffer: STAGE(next) issued before ds_read+MFMA(cur); the
// single __syncthreads (compiler emits vmcnt(0) drain) per K-step both
// completes the staging and orders the buffer swap.
// ---------------------------------------------------------------------------
template<bool SPLIT, int BM, int WPE>
__global__ __launch_bounds__(256, WPE)
void gemm_f16(const half_t* __restrict__ Ah, const half_t* __restrict__ Al,
              const half_t* __restrict__ Bth, const half_t* __restrict__ Btl,
              const float* __restrict__ bias, const float* __restrict__ res,
              float* __restrict__ Cf, half_t* __restrict__ Ch,
              int M, int N, int K)
{
    constexpr int NBUF = SPLIT ? 2 : 1;
    constexpr int MR = BM / 32;                  // m-frags per wave
    __shared__ half_t As[2][NBUF][BM * 32];
    __shared__ half_t Bs[2][NBUF][128 * 32];
    const int tid = threadIdx.x, lane = tid & 63, wid = tid >> 6;
    const int l15 = lane & 15, l4 = lane >> 4;
    const int row0 = blockIdx.y * BM, col0 = blockIdx.x * 128;
    const int wr = (wid >> 1) * (BM / 2), wc = (wid & 1) * 64;
    f32x4 accM[MR][4] = {}, accC[MR][4] = {};
    const int lrw = lane >> 2, lcl = (lane & 3) * 8;

#define STAGE(BUF, K0)                                                        \
    do {                                                                      \
        _Pragma("unroll")                                                     \
        for (int j = 0; j < BM / 64; ++j) {                                   \
            const int r = wid * (BM / 4) + j * 16;                            \
            const size_t ga = (size_t)(row0 + r + lrw) * K + (K0) + lcl;      \
            gload_lds16(Ah + ga, &As[BUF][0][r * 32]);                        \
            if constexpr (SPLIT) gload_lds16(Al + ga, &As[BUF][1][r * 32]);   \
        }                                                                     \
        _Pragma("unroll")                                                     \
        for (int j = 0; j < 2; ++j) {                                         \
            const int r = wid * 32 + j * 16;                                  \
            const size_t gb = (size_t)(col0 + r + lrw) * K + (K0) + lcl;      \
            gload_lds16(Bth + gb, &Bs[BUF][0][r * 32]);                       \
            if constexpr (SPLIT) gload_lds16(Btl + gb, &Bs[BUF][1][r * 32]);  \
        }                                                                     \
    } while (0)

    STAGE(0, 0);
    __syncthreads();
    int cur = 0;
    for (int k0 = 0; k0 < K; k0 += 32, cur ^= 1) {
        if (k0 + 32 < K) STAGE(cur ^ 1, k0 + 32);   // overlaps with MFMA below
        half8 ah[MR], al[MR], bh[4], bl[4];
#pragma unroll
        for (int m = 0; m < MR; ++m) {
            int off = (wr + m * 16 + l15) * 32 + l4 * 8;
            ah[m] = *(const half8*)&As[cur][0][off];
            if constexpr (SPLIT) al[m] = *(const half8*)&As[cur][1][off];
        }
#pragma unroll
        for (int n = 0; n < 4; ++n) {
            int off = (wc + n * 16 + l15) * 32 + l4 * 8;
            bh[n] = *(const half8*)&Bs[cur][0][off];
            if constexpr (SPLIT) bl[n] = *(const half8*)&Bs[cur][1][off];
        }
#pragma unroll
        for (int m = 0; m < MR; ++m)
#pragma unroll
            for (int n = 0; n < 4; ++n) {
                accM[m][n] = MFMA16(ah[m], bh[n], accM[m][n]);
                if constexpr (SPLIT) {
                    accC[m][n] = MFMA16(ah[m], bl[n], accC[m][n]);
                    accC[m][n] = MFMA16(al[m], bh[n], accC[m][n]);
                }
            }
        __syncthreads();   // drains staging vmcnt + orders buffer reuse
    }
#undef STAGE

#pragma unroll
    for (int m = 0; m < MR; ++m) {
#pragma unroll
        for (int n = 0; n < 4; ++n) {
            int gr0 = row0 + wr + m * 16 + l4 * 4;
            int gc  = col0 + wc + n * 16 + l15;
            float b = bias ? bias[gc] : 0.0f;
#pragma unroll
            for (int i = 0; i < 4; ++i) {
                float v = accM[m][n][i];
                if constexpr (SPLIT) v += accC[m][n][i] * (1.0f / 1024.0f);
                v += b;
                size_t idx = (size_t)(gr0 + i) * N + gc;
                if (res) v += res[idx];
                if (Cf) Cf[idx] = v;
                if (Ch) Ch[idx] = (half_t)v;
            }
        }
    }
}

// ---------------------------------------------------------------------------
// qkv post-processing: k-rmsnorm, RoPE on q/k (last 64 dims), Q pre-scaled by
// 128^-0.5, split-f16 outputs.
// ---------------------------------------------------------------------------
__global__ __launch_bounds__(256)
void qkv_prep(const float* __restrict__ qkv, const int* __restrict__ pos,
              const float* __restrict__ klnw,
              half_t* __restrict__ qh, half_t* __restrict__ ql,
              half_t* __restrict__ kh, half_t* __restrict__ kl)
{
    const int t = blockIdx.x, tid = threadIdx.x, lane = tid & 63, wid = tid >> 6;
    const float* row = qkv + (size_t)t * QKV_N;
    __shared__ float cs[32], sn[32];
    if (tid < 32) {
        double freq = exp((double)tid * -0.28782313662425572);  // -ln(1e4)/32
        double ang = (double)pos[t] * freq;
        const double twopi = 6.283185307179586476925286766559;
        ang -= twopi * floor(ang * (1.0 / twopi));
        float a = (float)ang;
        cs[tid] = cosf(a);
        sn[tid] = sinf(a);
    }
    __syncthreads();

    const float qscale = 0.08838834764831845f;   // 128^-0.5
    {
        const int hh = tid >> 4, d0 = (tid & 15) * 8;
        const float* qrow = row + hh * HD;
        float outv[8];
        if (d0 < 64) {
#pragma unroll
            for (int j = 0; j < 8; ++j) outv[j] = qrow[d0 + j];
        } else if (d0 < 96) {
            int j0 = d0 - 64;
#pragma unroll
            for (int j = 0; j < 8; ++j) {
                int jj = j0 + j;
                outv[j] = qrow[64 + jj] * cs[jj] - qrow[96 + jj] * sn[jj];
            }
        } else {
            int j0 = d0 - 96;
#pragma unroll
            for (int j = 0; j < 8; ++j) {
                int jj = j0 + j;
                outv[j] = qrow[64 + jj] * sn[jj] + qrow[96 + jj] * cs[jj];
            }
        }
        half8 hv, lv;
#pragma unroll
        for (int j = 0; j < 8; ++j) {
            float o = outv[j] * qscale;
            half_t h = (half_t)o;
            hv[j] = h;
            lv[j] = (half_t)((o - (float)h) * 1024.0f);
        }
        size_t base = (size_t)t * (NH * HD) + hh * HD + d0;
        *(half8*)(qh + base) = hv;
        *(half8*)(ql + base) = lv;
    }
    {
        const float* krow = row + NH * HD + wid * HD;
        float a0 = krow[lane], a1 = krow[64 + lane];
        float ss = a0 * a0 + a1 * a1;
        for (int o = 32; o; o >>= 1) ss += __shfl_down(ss, o);
        ss = __shfl(ss, 0);
        float rs = rsqrtf(ss * (1.0f / HD) + 1e-6f);
        float n0 = a0 * rs * klnw[lane];
        float n1 = a1 * rs * klnw[64 + lane];
        float other = __shfl_xor(n1, 32);
        int j = lane & 31;
        float o1 = (lane < 32) ? (n1 * cs[j] - other * sn[j])
                               : (other * sn[j] + n1 * cs[j]);
        size_t base = (size_t)t * (NKVH * HD) + wid * HD;
        half_t h;
        h = (half_t)n0; kh[base + lane] = h;
        kl[base + lane] = (half_t)((n0 - (float)h) * 1024.0f);
        h = (half_t)o1; kh[base + 64 + lane] = h;
        kl[base + 64 + lane] = (half_t)((o1 - (float)h) * 1024.0f);
    }
}

// ---------------------------------------------------------------------------
// Chunked flash attention, causal GQA, split-f16 MFMA. 4 waves x 16 q-rows.
// Block = (h, q-block, chunk of <=16 kv-tiles). 1280 near-uniform blocks,
// 3 blocks/CU. Single-chunk q-blocks (q<8) write final; others write fp32
// partials (O-unnorm, m, l) merged by attn_combine.
// ---------------------------------------------------------------------------
__global__ __launch_bounds__(256, 3)
void attn_kernel(const half_t* __restrict__ qh, const half_t* __restrict__ ql,
                 const half_t* __restrict__ kh, const half_t* __restrict__ kl,
                 const half_t* __restrict__ vth, const half_t* __restrict__ vtl,
                 half_t* __restrict__ oh, half_t* __restrict__ ol,
                 float* __restrict__ Op0, float* __restrict__ Op1,
                 float* __restrict__ ml)
{
    const int bid = blockIdx.x;
    const int h = bid & 15, r = bid >> 4;
    int q, c;
    if (r < 8)       { q = r;                 c = 0; }
    else if (r < 24) { q = 8 + ((r - 8) >> 1);  c = (r - 8) & 1; }
    else if (r < 48) { q = 16 + (r - 24) / 3;   c = (r - 24) % 3; }
    else             { q = 24 + ((r - 48) >> 2); c = (r - 48) & 3; }
    const int nch = (q < 8) ? 1 : (q < 16) ? 2 : (q < 24) ? 3 : 4;
    const int kvbeg = c * 512;
    const int kvend = min(kvbeg + 512, q * 64 + 64);

    const int kvh = h >> 2;
    const int tid = threadIdx.x, lane = tid & 63, wid = tid >> 6;
    const int q0 = q * 64 + wid * 16;
    const int l15 = lane & 15, l4 = lane >> 4;

    __shared__ half_t Ksh[32][136], Ksl[32][136];
    __shared__ half_t Vsh[128][40], Vsl[128][40];
    __shared__ half_t Ph[4][16][40], Pl[4][16][40];

    half8 qfh[4], qfl[4];
    {
        const size_t qb = (size_t)(q0 + l15) * (NH * HD) + h * HD + l4 * 8;
#pragma unroll
        for (int cc = 0; cc < 4; ++cc) {
            qfh[cc] = *(const half8*)(qh + qb + cc * 32);
            qfl[cc] = *(const half8*)(ql + qb + cc * 32);
        }
    }

    f32x4 om[8] = {}, oc[8] = {};
    float mrow[4] = { -1e30f, -1e30f, -1e30f, -1e30f };
    float lrow[4] = {};

    const int kr = tid >> 4, kc = (tid & 15) * 8;
    const int vd = tid >> 2, vc = (tid & 3) * 8;
    // NAMED prefetch registers (arrays get demoted to scratch - rule #20)
    uint4 rk0h, rk1h, rk0l, rk1l, rv0h, rv1h, rv0l, rv1l;

#define LOAD_TILE(KV0)                                                        \
    do {                                                                      \
        size_t sk0 = (size_t)((KV0) + kr) * (NKVH * HD) + kvh * HD + kc;      \
        size_t sk1 = sk0 + (size_t)16 * (NKVH * HD);                          \
        rk0h = *(const uint4*)(kh + sk0);  rk0l = *(const uint4*)(kl + sk0);  \
        rk1h = *(const uint4*)(kh + sk1);  rk1l = *(const uint4*)(kl + sk1);  \
        size_t sv0 = (size_t)(kvh * HD + vd) * T_TOK + (KV0) + vc;            \
        size_t sv1 = sv0 + (size_t)64 * T_TOK;                                \
        rv0h = *(const uint4*)(vth + sv0); rv0l = *(const uint4*)(vtl + sv0); \
        rv1h = *(const uint4*)(vth + sv1); rv1l = *(const uint4*)(vtl + sv1); \
    } while (0)

    LOAD_TILE(kvbeg);
    for (int kv0 = kvbeg; kv0 < kvend; kv0 += 32) {
        *(uint4*)&Ksh[kr][kc]      = rk0h;  *(uint4*)&Ksl[kr][kc]      = rk0l;
        *(uint4*)&Ksh[kr + 16][kc] = rk1h;  *(uint4*)&Ksl[kr + 16][kc] = rk1l;
        *(uint4*)&Vsh[vd][vc]      = rv0h;  *(uint4*)&Vsl[vd][vc]      = rv0l;
        *(uint4*)&Vsh[vd + 64][vc] = rv1h;  *(uint4*)&Vsl[vd + 64][vc] = rv1l;
        __syncthreads();
        if (kv0 + 32 < kvend) LOAD_TILE(kv0 + 32);   // overlaps compute

        f32x4 sf[2];
        __builtin_amdgcn_s_setprio(1);
#pragma unroll
        for (int t2 = 0; t2 < 2; ++t2) {       // S = Q K^T (pre-scaled Q)
            f32x4 s = {}, sc = {};
#pragma unroll
            for (int cc = 0; cc < 4; ++cc) {
                half8 bh = *(const half8*)&Ksh[t2 * 16 + l15][cc * 32 + l4 * 8];
                half8 bl = *(const half8*)&Ksl[t2 * 16 + l15][cc * 32 + l4 * 8];
                s  = MFMA16(qfh[cc], bh, s);
                sc = MFMA16(qfh[cc], bl, sc);
                sc = MFMA16(qfl[cc], bh, sc);
            }
            sf[t2] = s + sc * (1.0f / 1024.0f);
        }
        __builtin_amdgcn_s_setprio(0);

        float pmax[4];
#pragma unroll
        for (int i = 0; i < 4; ++i) {
            const int qg = q0 + l4 * 4 + i;
#pragma unroll
            for (int t2 = 0; t2 < 2; ++t2) {
                int kvg = kv0 + t2 * 16 + l15;
                if (kvg > qg) sf[t2][i] = -1e30f;
            }
            float mx = fmaxf(sf[0][i], sf[1][i]);
#pragma unroll
            for (int o = 1; o < 16; o <<= 1) mx = fmaxf(mx, __shfl_xor(mx, o));
            pmax[i] = mx;
        }
        float dm = fmaxf(fmaxf(pmax[0] - mrow[0], pmax[1] - mrow[1]),
                         fmaxf(pmax[2] - mrow[2], pmax[3] - mrow[3]));
        if (__any(dm > 6.0f)) {                // defer-max: rescale rarely
#pragma unroll
            for (int i = 0; i < 4; ++i) {
                float mnew = fmaxf(mrow[i], pmax[i]);
                float resc = expf(mrow[i] - mnew);
                lrow[i] *= resc;
#pragma unroll
                for (int c8 = 0; c8 < 8; ++c8) {
                    om[c8][i] *= resc; oc[c8][i] *= resc;
                }
                mrow[i] = mnew;
            }
        }
#pragma unroll
        for (int i = 0; i < 4; ++i) {
            float p0 = expf(sf[0][i] - mrow[i]);
            float p1 = expf(sf[1][i] - mrow[i]);
            lrow[i] += p0 + p1;
            half_t hh;
            hh = (half_t)p0;
            Ph[wid][l4 * 4 + i][l15] = hh;
            Pl[wid][l4 * 4 + i][l15] = (half_t)((p0 - (float)hh) * 1024.0f);
            hh = (half_t)p1;
            Ph[wid][l4 * 4 + i][16 + l15] = hh;
            Pl[wid][l4 * 4 + i][16 + l15] = (half_t)((p1 - (float)hh) * 1024.0f);
        }

        half8 pah = *(const half8*)&Ph[wid][l15][l4 * 8];
        half8 pal = *(const half8*)&Pl[wid][l15][l4 * 8];
        __builtin_amdgcn_s_setprio(1);
#pragma unroll
        for (int c8 = 0; c8 < 8; ++c8) {       // O += P V
            half8 vh = *(const half8*)&Vsh[c8 * 16 + l15][l4 * 8];
            half8 vl = *(const half8*)&Vsl[c8 * 16 + l15][l4 * 8];
            om[c8] = MFMA16(pah, vh, om[c8]);
            oc[c8] = MFMA16(pah, vl, oc[c8]);
            oc[c8] = MFMA16(pal, vh, oc[c8]);
        }
        __builtin_amdgcn_s_setprio(0);
        __syncthreads();
    }
#undef LOAD_TILE

#pragma unroll
    for (int i = 0; i < 4; ++i)
#pragma unroll
        for (int o = 1; o < 16; o <<= 1) lrow[i] += __shfl_xor(lrow[i], o);

    if (nch == 1) {
#pragma unroll
        for (int c8 = 0; c8 < 8; ++c8) {
#pragma unroll
            for (int i = 0; i < 4; ++i) {
                float v = (om[c8][i] + oc[c8][i] * (1.0f / 1024.0f)) / lrow[i];
                size_t idx = (size_t)(q0 + l4 * 4 + i) * (NH * HD) + h * HD
                           + c8 * 16 + l15;
                half_t hh = (half_t)v;
                oh[idx] = hh;
                ol[idx] = (half_t)((v - (float)hh) * 1024.0f);
            }
        }
    } else {
        float* Op = (bid < 768) ? Op0 + (size_t)bid * 8192
                                : Op1 + (size_t)(bid - 768) * 8192;
#pragma unroll
        for (int c8 = 0; c8 < 8; ++c8) {
#pragma unroll
            for (int i = 0; i < 4; ++i) {
                int row64 = wid * 16 + l4 * 4 + i;
                Op[row64 * 128 + c8 * 16 + l15] =
                    om[c8][i] + oc[c8][i] * (1.0f / 1024.0f);
            }
        }
        if (l15 == 0) {
#pragma unroll
            for (int i = 0; i < 4; ++i) {
                int row64 = wid * 16 + l4 * 4 + i;
                ml[(size_t)bid * 128 + row64]      = mrow[i];
                ml[(size_t)bid * 128 + 64 + row64] = lrow[i];
            }
        }
    }
}

// ---------------------------------------------------------------------------
// Combine partial attention chunks (q >= 8): exact online-softmax merge in
// fp32, write split-f16 attn. Grid 24(q) x 16(h) = 384 blocks.
// ---------------------------------------------------------------------------
__global__ __launch_bounds__(256)
void attn_combine(const float* __restrict__ Op0, const float* __restrict__ Op1,
                  const float* __restrict__ ml,
                  half_t* __restrict__ oh, half_t* __restrict__ ol)
{
    const int bid = blockIdx.x;
    const int h = bid & 15, q = 8 + (bid >> 4);
    const int nch = (q < 16) ? 2 : (q < 24) ? 3 : 4;
    const int r0 = (q < 16) ? 8 + (q - 8) * 2
                 : (q < 24) ? 24 + (q - 16) * 3
                            : 48 + (q - 24) * 4;
    const int tid = threadIdx.x;
    const int row = tid >> 2, cg = (tid & 3) * 32;

    const float* Oc[4];
    float m[4], lv[4];
#pragma unroll
    for (int c = 0; c < 4; ++c) {
        int cc = (c < nch) ? c : nch - 1;
        int slot = (r0 + cc) * 16 + h;
        const float* base = (slot < 768) ? Op0 + (size_t)slot * 8192
                                         : Op1 + (size_t)(slot - 768) * 8192;
        Oc[c] = base + row * 128 + cg;
        m[c]  = ml[(size_t)slot * 128 + row];
        lv[c] = (c < nch) ? ml[(size_t)slot * 128 + 64 + row] : 0.0f;
    }
    float M = fmaxf(fmaxf(m[0], m[1]), fmaxf(m[2], m[3]));
    float w[4], wsum = 0.0f;
#pragma unroll
    for (int c = 0; c < 4; ++c) { w[c] = expf(m[c] - M); wsum += lv[c] * w[c]; }
    float inv = 1.0f / wsum;
    float wO[4];
#pragma unroll
    for (int c = 0; c < 4; ++c) wO[c] = (c < nch) ? w[c] * inv : 0.0f;

    size_t obase = (size_t)(q * 64 + row) * (NH * HD) + h * HD + cg;
#pragma unroll
    for (int jj = 0; jj < 4; ++jj) {
        floatx4 a0 = {0,0,0,0}, a1 = {0,0,0,0};
#pragma unroll
        for (int c = 0; c < 4; ++c) {
            floatx4 v0 = *(const floatx4*)(Oc[c] + jj * 8);
            floatx4 v1 = *(const floatx4*)(Oc[c] + jj * 8 + 4);
            a0 += wO[c] * v0;
            a1 += wO[c] * v1;
        }
        half8 hv, lvv;
#pragma unroll
        for (int k = 0; k < 4; ++k) {
            half_t hh = (half_t)a0[k];
            hv[k] = hh; lvv[k] = (half_t)((a0[k] - (float)hh) * 1024.0f);
            hh = (half_t)a1[k];
            hv[4 + k] = hh; lvv[4 + k] = (half_t)((a1[k] - (float)hh) * 1024.0f);
        }
        *(half8*)(oh + obase + jj * 8) = hv;
        *(half8*)(ol + obase + jj * 8) = lvv;
    }
}

// ---------------------------------------------------------------------------
// Linear router: logit_e = rs(x2) * ( x.u_e + attn_precise . ow_u_e ).
// ---------------------------------------------------------------------------
__global__ __launch_bounds__(256)
void router_linear(const float* __restrict__ x, const half_t* __restrict__ ah,
                   const half_t* __restrict__ al, const float* __restrict__ x2,
                   const float* __restrict__ ln2w, const float* __restrict__ rw,
                   const float* __restrict__ owu, float* __restrict__ combine)
{
    const int t = blockIdx.x, tid = threadIdx.x;
    const float* xr2 = x2 + (size_t)t * HIDN;
    float ss = 0.0f;
#pragma unroll
    for (int i = 0; i < 8; ++i) {
        float v = xr2[tid + i * 256];
        ss += v * v;
    }
    for (int o = 32; o; o >>= 1) ss += __shfl_down(ss, o);
    __shared__ float red[4];
    if ((tid & 63) == 0) red[tid >> 6] = ss;
    __syncthreads();
    ss = red[0] + red[1] + red[2] + red[3];
    float rs = rsqrtf(ss * (1.0f / HIDN) + 1e-6f);

    const float* xr = x + (size_t)t * HIDN;
    const half_t* ar = ah + (size_t)t * HIDN;
    const half_t* alr = al + (size_t)t * HIDN;
    float acc[NEXP] = {};
#pragma unroll
    for (int i = 0; i < 8; ++i) {
        int c = tid + i * 256;
        float xv = xr[c] * ln2w[c];
        float ap = (float)ar[c] + (float)alr[c] * (1.0f / 1024.0f);
        const float* rwc = rw + (size_t)c * NEXP;
        const float* owc = owu + (size_t)c * NEXP;
#pragma unroll
        for (int e = 0; e < NEXP; ++e) acc[e] += xv * rwc[e] + ap * owc[e];
    }
#pragma unroll
    for (int e = 0; e < NEXP; ++e)
        for (int o = 32; o; o >>= 1) acc[e] += __shfl_down(acc[e], o);
    __shared__ float red8[4][NEXP];
    if ((tid & 63) == 0)
#pragma unroll
        for (int e = 0; e < NEXP; ++e) red8[tid >> 6][e] = acc[e];
    __syncthreads();
    if (tid == 0) {
        float lg[NEXP];
#pragma unroll
        for (int e = 0; e < NEXP; ++e)
            lg[e] = (red8[0][e] + red8[1][e] + red8[2][e] + red8[3][e]) * rs;
        int i1 = 0;
        for (int e = 1; e < NEXP; ++e) if (lg[e] > lg[i1]) i1 = e;
        int i2 = (i1 == 0) ? 1 : 0;
        for (int e = 0; e < NEXP; ++e) if (e != i1 && lg[e] > lg[i2]) i2 = e;
        float mx = lg[i1];
        float p1 = expf(lg[i1] - mx), p2 = expf(lg[i2] - mx);
        float inv = 1.0f / (p1 + p2);
        float* cr = combine + (size_t)t * NEXP;
#pragma unroll
        for (int e = 0; e < NEXP; ++e) cr[e] = 0.0f;
        cr[i1] = p1 * inv;
        cr[i2] = p2 * inv;
    }
}

// ---------------------------------------------------------------------------
// MoE activation: Abig[t][n] = scale * silu(G[t][n]) * U[t][n]
// ---------------------------------------------------------------------------
__global__ __launch_bounds__(256)
void moe_act(const half_t* __restrict__ GU, const float* __restrict__ comb,
             half_t* __restrict__ Abig)
{
    int idx = blockIdx.x * 256 + threadIdx.x;
    int t = idx / 640, c8 = idx % 640;
    int n = c8 * 8;
    half8 g8 = *(const half8*)(GU + (size_t)t * 10240 + n);
    half8 u8 = *(const half8*)(GU + (size_t)t * 10240 + 5120 + n);
    float sc = (n < 1024) ? 1.0f : comb[(size_t)t * NEXP + ((n - 1024) >> 9)];
    half8 o8;
#pragma unroll
    for (int j = 0; j < 8; ++j) {
        float g = (float)g8[j], u = (float)u8[j];
        float s = g / (1.0f + expf(-g));
        o8[j] = (half_t)(s * u * sc);
    }
    *(half8*)(Abig + (size_t)t * 5120 + n) = o8;
}

// ---------------------------------------------------------------------------
extern "C" void kernel_launch(void* const* d_in, const int* in_sizes, int n_in,
                              void* d_out, int out_size, void* d_ws, size_t ws_size,
                              hipStream_t stream)
{
    (void)in_sizes; (void)n_in; (void)out_size; (void)ws_size;
    const float* x    = (const float*)d_in[0];
    const int*   pos  = (const int*)  d_in[1];
    const float* ln1w = (const float*)d_in[2];
    const float* qkvw = (const float*)d_in[3];
    const float* qkvb = (const float*)d_in[4];
    const float* klnw = (const float*)d_in[5];
    const float* ow   = (const float*)d_in[6];
    const float* ln2w = (const float*)d_in[7];
    const float* rw   = (const float*)d_in[8];
    const float* w1   = (const float*)d_in[9];
    const float* w2   = (const float*)d_in[10];
    const float* w3   = (const float*)d_in[11];
    const float* sw1  = (const float*)d_in[12];
    const float* sw2  = (const float*)d_in[13];
    const float* sw3  = (const float*)d_in[14];
    float* out = (float*)d_out;

    // ---- workspace arena (phase-overlapped; total 142,671,872 B) ----
    char* ws = (char*)d_ws;
    const size_t AB = 16842752;
    float*  x2      = (float*)(ws);                   // also Opart1 (512 slots)
    float*  combine = (float*)(ws + 16777216);
    half_t* h_hi    = (half_t*)(ws + AB);
    half_t* h_lo    = (half_t*)(ws + AB + 8388608);
    half_t* qkvwt_h = (half_t*)(ws + AB + 16777216);
    half_t* qkvwt_l = (half_t*)(ws + AB + 29360128);
    float*  qkv     = (float*)(ws + AB + 41943040);   // also Opart0 (768 slots)
    half_t* q_h     = (half_t*)(ws + AB + 67108864);
    half_t* q_l     = (half_t*)(ws + AB + 75497472);
    half_t* k_h     = (half_t*)(ws + AB + 83886080);
    half_t* k_l     = (half_t*)(ws + AB + 85983232);
    half_t* vt_h    = (half_t*)(ws + AB + 88080384);
    half_t* vt_l    = (half_t*)(ws + AB + 90177536);
    half_t* attn_h  = (half_t*)(ws + AB);             // reuse h_hi
    half_t* attn_l  = (half_t*)(ws + AB + 8388608);   // reuse h_lo
    half_t* owt     = (half_t*)(ws + AB + 16777216);  // reuse qkvwt_h
    float*  ow_u    = (float*)(ws + AB + 25165824);   // 64 KB
    float*  mlpart  = (float*)(ws + AB + 25231360);   // 656 KB (dead qkvwt)
    float*  Opart0  = (float*)(ws + AB + 41943040);   // = qkv region (25.2MB)
    float*  Opart1  = (float*)(ws);                   // = x2 region (16.8MB)
    half_t* h2      = (half_t*)(ws + AB + 33554432);
    half_t* W13t    = (half_t*)(ws + AB + 41943040);  // reuse qkv + q (dead)
    half_t* GU      = (half_t*)(ws + AB + 83886080);  // reuse k/vt (dead)
    half_t* Abig    = (half_t*)(ws + AB);             // reuse attn (dead)
    half_t* W2t     = (half_t*)(ws + AB + 41943040);  // reuse W13t (dead)

    dim3 b256(256);

    // 1. h = rmsnorm(x, ln1_w) split
    rmsnorm_split_k<<<T_TOK, b256, 0, stream>>>(x, ln1w, h_hi, h_lo);
    // 2. qkv_w -> transposed split f16
    transpose_split2<<<dim3(QKV_N / 32, HIDN / 32), b256, 0, stream>>>(
        qkvw, qkvwt_h, qkvwt_l, QKV_N, HIDN);
    // 3. qkv = h @ qkv_w + b   (split path, 3 blocks/CU)
    gemm_f16<true, 64, 3><<<dim3(QKV_N / 128, T_TOK / 64), b256, 0, stream>>>(
        h_hi, h_lo, qkvwt_h, qkvwt_l, qkvb, nullptr, qkv, nullptr,
        T_TOK, QKV_N, HIDN);
    // 4. k-rmsnorm + rope + split (q pre-scaled)
    qkv_prep<<<T_TOK, b256, 0, stream>>>(qkv, pos, klnw, q_h, q_l, k_h, k_l);
    // 5. v^T: vt[d][t] = qkv[t][2560+d] (split)
    transpose_split2<<<dim3(512 / 32, T_TOK / 32), b256, 0, stream>>>(
        qkv + 2560, vt_h, vt_l, QKV_N, T_TOK);
    // 6. o_w transpose (single f16)
    transpose_f16<<<dim3(HIDN / 64, HIDN / 32), b256, 0, stream>>>(
        ow, owt, HIDN, HIDN);
    // 7. ow_u = o_w @ (ln2w * rw)   (fp32 router projection)
    owu_kernel<<<512, b256, 0, stream>>>(ow, ln2w, rw, ow_u);
    // 8. attention (chunked KV, 1280 blocks, 3/CU)
    attn_kernel<<<1280, b256, 0, stream>>>(
        q_h, q_l, k_h, k_l, vt_h, vt_l, attn_h, attn_l,
        Opart0, Opart1, mlpart);
    // 8b. combine partial chunks (q >= 8)
    attn_combine<<<384, b256, 0, stream>>>(Opart0, Opart1, mlpart,
                                           attn_h, attn_l);
    // 9. x2 = x + attn @ o_w   (single f16; router bypasses this)
    gemm_f16<false, 64, 2><<<dim3(HIDN / 128, T_TOK / 64), b256, 0, stream>>>(
        attn_h, nullptr, owt, nullptr, nullptr, x, x2, nullptr,
        T_TOK, HIDN, HIDN);
    // 10. router (exact linear path) -> combine weights
    router_linear<<<T_TOK, b256, 0, stream>>>(
        x, attn_h, attn_l, x2, ln2w, rw, ow_u, combine);
    // 11. h2 = rmsnorm(x2, ln2_w), single f16
    rmsnorm_split_k<<<T_TOK, b256, 0, stream>>>(x2, ln2w, h2, nullptr);
    // 12. W13t batched transpose (1 launch)
    w13_transpose<<<dim3(10240 / 64, HIDN / 32), b256, 0, stream>>>(
        sw1, w1, sw3, w3, W13t);
    // 13. GU = h2 @ [W1|W3]  (single f16, f16 out, 3 blocks/CU)
    gemm_f16<false, 128, 3><<<dim3(10240 / 128, T_TOK / 128), b256, 0, stream>>>(
        h2, nullptr, W13t, nullptr, nullptr, nullptr, nullptr, GU,
        T_TOK, 10240, HIDN);
    // 14. W2t batched transpose (1 launch)
    w2_transpose<<<dim3(HIDN / 64, 5120 / 32), b256, 0, stream>>>(sw2, w2, W2t);
    // 15. Abig = combine-scaled silu(G)*U
    moe_act<<<(T_TOK * 640) / 256, b256, 0, stream>>>(GU, combine, Abig);
    // 16. out = x2 + Abig @ W2cat
    gemm_f16<false, 64, 2><<<dim3(HIDN / 128, T_TOK / 64), b256, 0, stream>>>(
        Abig, nullptr, W2t, nullptr, nullptr, x2, out, nullptr,
        T_TOK, HIDN, 5120);
}

// Round 6
// 650.641 us; speedup vs baseline: 1.1133x; 1.1133x over previous
//
#include <hip/hip_runtime.h>

// ---------------------------------------------------------------------------
// PanguProMoE decoder layer, MI355X (gfx950).
// Precision: qkv GEMM + attention in split-f16 ("f16x2": x = hi + lo/1024,
// 3 MFMAs/tile). Router logits via exact linear path (see router_linear).
// Post-router MoE in plain f16. RoPE angles in double.
// R6: revert all kernels to min-waves/EU = 2. R5 evidence: launch_bounds
// (256,3) caps the allocator at ~85 VGPRs -> split-f16 kernels (need ~104+)
// spill accumulators to scratch (WRITE_SIZE 16->279MB, attn 141->203us).
// Chunked-KV attention kept (occupancy fix was real: 13->23%).
// ---------------------------------------------------------------------------

typedef _Float16 half_t;
typedef _Float16 half8 __attribute__((ext_vector_type(8)));
typedef float    f32x4 __attribute__((ext_vector_type(4)));
typedef float    floatx4 __attribute__((ext_vector_type(4)));

#define T_TOK 2048
#define HIDN  2048
#define NH    16
#define NKVH  4
#define HD    128
#define QKV_N 3072
#define NEXP  8

#define MFMA16(a,b,c) __builtin_amdgcn_mfma_f32_16x16x32_f16(a,b,c,0,0,0)

__device__ __forceinline__ void gload_lds16(const half_t* g, half_t* l) {
    __builtin_amdgcn_global_load_lds(
        (const __attribute__((address_space(1))) void*)g,
        (__attribute__((address_space(3))) void*)l, 16, 0, 0);
}

// ---------------------------------------------------------------------------
// rmsnorm over HIDN cols, write split f16 (lo optional)
// ---------------------------------------------------------------------------
__global__ __launch_bounds__(256)
void rmsnorm_split_k(const float* __restrict__ x, const float* __restrict__ w,
                     half_t* __restrict__ hi, half_t* __restrict__ lo)
{
    const int row = blockIdx.x, tid = threadIdx.x;
    const float* xr = x + (size_t)row * HIDN;
    floatx4 v0 = *(const floatx4*)(xr + tid * 8);
    floatx4 v1 = *(const floatx4*)(xr + tid * 8 + 4);
    float ss = v0[0]*v0[0] + v0[1]*v0[1] + v0[2]*v0[2] + v0[3]*v0[3]
             + v1[0]*v1[0] + v1[1]*v1[1] + v1[2]*v1[2] + v1[3]*v1[3];
    for (int o = 32; o; o >>= 1) ss += __shfl_down(ss, o);
    __shared__ float red[4];
    if ((tid & 63) == 0) red[tid >> 6] = ss;
    __syncthreads();
    ss = red[0] + red[1] + red[2] + red[3];
    float rs = rsqrtf(ss * (1.0f / HIDN) + 1e-6f);
    floatx4 w0 = *(const floatx4*)(w + tid * 8);
    floatx4 w1 = *(const floatx4*)(w + tid * 8 + 4);
    float vv[8] = { v0[0]*w0[0], v0[1]*w0[1], v0[2]*w0[2], v0[3]*w0[3],
                    v1[0]*w1[0], v1[1]*w1[1], v1[2]*w1[2], v1[3]*w1[3] };
    half8 hv, lv;
#pragma unroll
    for (int j = 0; j < 8; ++j) {
        float o = vv[j] * rs;
        half_t h = (half_t)o;
        hv[j] = h;
        lv[j] = (half_t)((o - (float)h) * 1024.0f);
    }
    *(half8*)(hi + (size_t)row * HIDN + tid * 8) = hv;
    if (lo) *(half8*)(lo + (size_t)row * HIDN + tid * 8) = lv;
}

// ---------------------------------------------------------------------------
// Transpose fp32 -> split f16: dst[n][k] = src[k][n]. 32x32 tile.
// ---------------------------------------------------------------------------
__global__ __launch_bounds__(256)
void transpose_split2(const float* __restrict__ src, half_t* __restrict__ dh,
                      half_t* __restrict__ dl, int sstride, int dstride)
{
    __shared__ float tile[32][36];
    const int n0 = blockIdx.x * 32, k0 = blockIdx.y * 32;
    const int tid = threadIdx.x;
    {
        int r = tid >> 3, c = (tid & 7) * 4;
        *(floatx4*)&tile[r][c] =
            *(const floatx4*)(src + (size_t)(k0 + r) * sstride + n0 + c);
    }
    __syncthreads();
    int n = tid & 31, g = tid >> 5, gg = g & 3;
    half8 hv;
    if (g < 4) {
#pragma unroll
        for (int j = 0; j < 8; ++j) hv[j] = (half_t)tile[gg * 8 + j][n];
        *(half8*)(dh + (size_t)(n0 + n) * dstride + k0 + gg * 8) = hv;
    } else {
#pragma unroll
        for (int j = 0; j < 8; ++j) {
            float v = tile[gg * 8 + j][n];
            half_t h = (half_t)v;
            hv[j] = (half_t)((v - (float)h) * 1024.0f);
        }
        *(half8*)(dl + (size_t)(n0 + n) * dstride + k0 + gg * 8) = hv;
    }
}

// ---------------------------------------------------------------------------
// Transpose fp32 -> single f16: dst[n][k] = src[k][n]. 32(k)x64(n) tile.
// ---------------------------------------------------------------------------
__global__ __launch_bounds__(256)
void transpose_f16(const float* __restrict__ src, half_t* __restrict__ dh,
                   int sstride, int dstride)
{
    __shared__ float tile[32][68];
    const int n0 = blockIdx.x * 64, k0 = blockIdx.y * 32;
    const int tid = threadIdx.x;
    {
        int r = tid >> 3, c = (tid & 7) * 4;
        const float* s = src + (size_t)(k0 + r) * sstride + n0;
        *(floatx4*)&tile[r][c]      = *(const floatx4*)(s + c);
        *(floatx4*)&tile[r][c + 32] = *(const floatx4*)(s + c + 32);
    }
    __syncthreads();
    int n = tid & 63, g = tid >> 6;
    half8 hv;
#pragma unroll
    for (int j = 0; j < 8; ++j) hv[j] = (half_t)tile[g * 8 + j][n];
    *(half8*)(dh + (size_t)(n0 + n) * dstride + k0 + g * 8) = hv;
}

// ---------------------------------------------------------------------------
// Batched W13 transpose: W13t[n][k] (n<10240, k<2048), f16.
// ---------------------------------------------------------------------------
__global__ __launch_bounds__(256)
void w13_transpose(const float* __restrict__ sw1, const float* __restrict__ w1,
                   const float* __restrict__ sw3, const float* __restrict__ w3,
                   half_t* __restrict__ dst)
{
    __shared__ float tile[32][68];
    const int n0 = blockIdx.x * 64, k0 = blockIdx.y * 32;
    const int tid = threadIdx.x;
    const float* base;
    int stride;
    if (n0 < 1024)      { base = sw1 + n0; stride = 1024; }
    else if (n0 < 5120) { int e = (n0 - 1024) >> 9;
                          base = w1 + (size_t)e * HIDN * 512 + ((n0 - 1024) & 511);
                          stride = 512; }
    else if (n0 < 6144) { base = sw3 + (n0 - 5120); stride = 1024; }
    else                { int e = (n0 - 6144) >> 9;
                          base = w3 + (size_t)e * HIDN * 512 + ((n0 - 6144) & 511);
                          stride = 512; }
    {
        int r = tid >> 3, c = (tid & 7) * 4;
        const float* s = base + (size_t)(k0 + r) * stride;
        *(floatx4*)&tile[r][c]      = *(const floatx4*)(s + c);
        *(floatx4*)&tile[r][c + 32] = *(const floatx4*)(s + c + 32);
    }
    __syncthreads();
    int n = tid & 63, g = tid >> 6;
    half8 hv;
#pragma unroll
    for (int j = 0; j < 8; ++j) hv[j] = (half_t)tile[g * 8 + j][n];
    *(half8*)(dst + (size_t)(n0 + n) * HIDN + k0 + g * 8) = hv;
}

// ---------------------------------------------------------------------------
// Batched W2 transpose: W2t[n][k] (n<2048, k<5120), f16, dstride 5120.
// ---------------------------------------------------------------------------
__global__ __launch_bounds__(256)
void w2_transpose(const float* __restrict__ sw2, const float* __restrict__ w2,
                  half_t* __restrict__ dst)
{
    __shared__ float tile[32][68];
    const int n0 = blockIdx.x * 64, k0 = blockIdx.y * 32;
    const int tid = threadIdx.x;
    {
        int r = tid >> 3, c = (tid & 7) * 4;
        int k = k0 + r;
        const float* s;
        if (k < 1024) s = sw2 + (size_t)k * HIDN + n0;
        else {
            int e = (k - 1024) >> 9, kk = (k - 1024) & 511;
            s = w2 + ((size_t)e * 512 + kk) * HIDN + n0;
        }
        *(floatx4*)&tile[r][c]      = *(const floatx4*)(s + c);
        *(floatx4*)&tile[r][c + 32] = *(const floatx4*)(s + c + 32);
    }
    __syncthreads();
    int n = tid & 63, g = tid >> 6;
    half8 hv;
#pragma unroll
    for (int j = 0; j < 8; ++j) hv[j] = (half_t)tile[g * 8 + j][n];
    *(half8*)(dst + (size_t)(n0 + n) * 5120 + k0 + g * 8) = hv;
}

// ---------------------------------------------------------------------------
// ow_u[k][e] = sum_c o_w[k][c] * ln2w[c] * rw[c][e]   (fp32, 2048x8)
// ---------------------------------------------------------------------------
__global__ __launch_bounds__(256)
void owu_kernel(const float* __restrict__ ow, const float* __restrict__ ln2w,
                const float* __restrict__ rw, float* __restrict__ owu)
{
    const int k = blockIdx.x * 4 + (threadIdx.x >> 6);
    const int lane = threadIdx.x & 63;
    float acc[NEXP] = {};
    const float* row = ow + (size_t)k * HIDN;
#pragma unroll
    for (int j = 0; j < 8; ++j) {
        int c = j * 256 + lane * 4;
        floatx4 ov = *(const floatx4*)(row + c);
        floatx4 lw = *(const floatx4*)(ln2w + c);
#pragma unroll
        for (int i = 0; i < 4; ++i) {
            float s = ov[i] * lw[i];
            const float* rwc = rw + (size_t)(c + i) * NEXP;
#pragma unroll
            for (int e = 0; e < NEXP; ++e) acc[e] += s * rwc[e];
        }
    }
#pragma unroll
    for (int e = 0; e < NEXP; ++e)
        for (int o = 32; o; o >>= 1) acc[e] += __shfl_down(acc[e], o);
    if (lane == 0) {
#pragma unroll
        for (int e = 0; e < NEXP; ++e) owu[(size_t)k * NEXP + e] = acc[e];
    }
}

// ---------------------------------------------------------------------------
// GEMM: C[M][N] = A[M][K] @ Bt[N][K]^T (+bias)(+res). f16 in, fp32 acc.
// SPLIT: (hi, lo*1024) pairs, 3 MFMAs/tile. BM x 128 tile, BK=32, 4 waves.
// 2-phase double-buffer: STAGE(next) issued before ds_read+MFMA(cur); one
// __syncthreads (vmcnt(0) drain) per K-step. min-waves/EU = 2 (3 caps VGPR
// at ~85 and spills -- R5 evidence).
// ---------------------------------------------------------------------------
template<bool SPLIT, int BM>
__global__ __launch_bounds__(256, 2)
void gemm_f16(const half_t* __restrict__ Ah, const half_t* __restrict__ Al,
              const half_t* __restrict__ Bth, const half_t* __restrict__ Btl,
              const float* __restrict__ bias, const float* __restrict__ res,
              float* __restrict__ Cf, half_t* __restrict__ Ch,
              int M, int N, int K)
{
    constexpr int NBUF = SPLIT ? 2 : 1;
    constexpr int MR = BM / 32;                  // m-frags per wave
    __shared__ half_t As[2][NBUF][BM * 32];
    __shared__ half_t Bs[2][NBUF][128 * 32];
    const int tid = threadIdx.x, lane = tid & 63, wid = tid >> 6;
    const int l15 = lane & 15, l4 = lane >> 4;
    const int row0 = blockIdx.y * BM, col0 = blockIdx.x * 128;
    const int wr = (wid >> 1) * (BM / 2), wc = (wid & 1) * 64;
    f32x4 accM[MR][4] = {}, accC[MR][4] = {};
    const int lrw = lane >> 2, lcl = (lane & 3) * 8;

#define STAGE(BUF, K0)                                                        \
    do {                                                                      \
        _Pragma("unroll")                                                     \
        for (int j = 0; j < BM / 64; ++j) {                                   \
            const int r = wid * (BM / 4) + j * 16;                            \
            const size_t ga = (size_t)(row0 + r + lrw) * K + (K0) + lcl;      \
            gload_lds16(Ah + ga, &As[BUF][0][r * 32]);                        \
            if constexpr (SPLIT) gload_lds16(Al + ga, &As[BUF][1][r * 32]);   \
        }                                                                     \
        _Pragma("unroll")                                                     \
        for (int j = 0; j < 2; ++j) {                                         \
            const int r = wid * 32 + j * 16;                                  \
            const size_t gb = (size_t)(col0 + r + lrw) * K + (K0) + lcl;      \
            gload_lds16(Bth + gb, &Bs[BUF][0][r * 32]);                       \
            if constexpr (SPLIT) gload_lds16(Btl + gb, &Bs[BUF][1][r * 32]);  \
        }                                                                     \
    } while (0)

    STAGE(0, 0);
    __syncthreads();
    int cur = 0;
    for (int k0 = 0; k0 < K; k0 += 32, cur ^= 1) {
        if (k0 + 32 < K) STAGE(cur ^ 1, k0 + 32);   // overlaps with MFMA below
        half8 ah[MR], al[MR], bh[4], bl[4];
#pragma unroll
        for (int m = 0; m < MR; ++m) {
            int off = (wr + m * 16 + l15) * 32 + l4 * 8;
            ah[m] = *(const half8*)&As[cur][0][off];
            if constexpr (SPLIT) al[m] = *(const half8*)&As[cur][1][off];
        }
#pragma unroll
        for (int n = 0; n < 4; ++n) {
            int off = (wc + n * 16 + l15) * 32 + l4 * 8;
            bh[n] = *(const half8*)&Bs[cur][0][off];
            if constexpr (SPLIT) bl[n] = *(const half8*)&Bs[cur][1][off];
        }
#pragma unroll
        for (int m = 0; m < MR; ++m)
#pragma unroll
            for (int n = 0; n < 4; ++n) {
                accM[m][n] = MFMA16(ah[m], bh[n], accM[m][n]);
                if constexpr (SPLIT) {
                    accC[m][n] = MFMA16(ah[m], bl[n], accC[m][n]);
                    accC[m][n] = MFMA16(al[m], bh[n], accC[m][n]);
                }
            }
        __syncthreads();   // drains staging vmcnt + orders buffer reuse
    }
#undef STAGE

#pragma unroll
    for (int m = 0; m < MR; ++m) {
#pragma unroll
        for (int n = 0; n < 4; ++n) {
            int gr0 = row0 + wr + m * 16 + l4 * 4;
            int gc  = col0 + wc + n * 16 + l15;
            float b = bias ? bias[gc] : 0.0f;
#pragma unroll
            for (int i = 0; i < 4; ++i) {
                float v = accM[m][n][i];
                if constexpr (SPLIT) v += accC[m][n][i] * (1.0f / 1024.0f);
                v += b;
                size_t idx = (size_t)(gr0 + i) * N + gc;
                if (res) v += res[idx];
                if (Cf) Cf[idx] = v;
                if (Ch) Ch[idx] = (half_t)v;
            }
        }
    }
}

// ---------------------------------------------------------------------------
// qkv post-processing: k-rmsnorm, RoPE on q/k (last 64 dims), Q pre-scaled by
// 128^-0.5, split-f16 outputs.
// ---------------------------------------------------------------------------
__global__ __launch_bounds__(256)
void qkv_prep(const float* __restrict__ qkv, const int* __restrict__ pos,
              const float* __restrict__ klnw,
              half_t* __restrict__ qh, half_t* __restrict__ ql,
              half_t* __restrict__ kh, half_t* __restrict__ kl)
{
    const int t = blockIdx.x, tid = threadIdx.x, lane = tid & 63, wid = tid >> 6;
    const float* row = qkv + (size_t)t * QKV_N;
    __shared__ float cs[32], sn[32];
    if (tid < 32) {
        double freq = exp((double)tid * -0.28782313662425572);  // -ln(1e4)/32
        double ang = (double)pos[t] * freq;
        const double twopi = 6.283185307179586476925286766559;
        ang -= twopi * floor(ang * (1.0 / twopi));
        float a = (float)ang;
        cs[tid] = cosf(a);
        sn[tid] = sinf(a);
    }
    __syncthreads();

    const float qscale = 0.08838834764831845f;   // 128^-0.5
    {
        const int hh = tid >> 4, d0 = (tid & 15) * 8;
        const float* qrow = row + hh * HD;
        float outv[8];
        if (d0 < 64) {
#pragma unroll
            for (int j = 0; j < 8; ++j) outv[j] = qrow[d0 + j];
        } else if (d0 < 96) {
            int j0 = d0 - 64;
#pragma unroll
            for (int j = 0; j < 8; ++j) {
                int jj = j0 + j;
                outv[j] = qrow[64 + jj] * cs[jj] - qrow[96 + jj] * sn[jj];
            }
        } else {
            int j0 = d0 - 96;
#pragma unroll
            for (int j = 0; j < 8; ++j) {
                int jj = j0 + j;
                outv[j] = qrow[64 + jj] * sn[jj] + qrow[96 + jj] * cs[jj];
            }
        }
        half8 hv, lv;
#pragma unroll
        for (int j = 0; j < 8; ++j) {
            float o = outv[j] * qscale;
            half_t h = (half_t)o;
            hv[j] = h;
            lv[j] = (half_t)((o - (float)h) * 1024.0f);
        }
        size_t base = (size_t)t * (NH * HD) + hh * HD + d0;
        *(half8*)(qh + base) = hv;
        *(half8*)(ql + base) = lv;
    }
    {
        const float* krow = row + NH * HD + wid * HD;
        float a0 = krow[lane], a1 = krow[64 + lane];
        float ss = a0 * a0 + a1 * a1;
        for (int o = 32; o; o >>= 1) ss += __shfl_down(ss, o);
        ss = __shfl(ss, 0);
        float rs = rsqrtf(ss * (1.0f / HD) + 1e-6f);
        float n0 = a0 * rs * klnw[lane];
        float n1 = a1 * rs * klnw[64 + lane];
        float other = __shfl_xor(n1, 32);
        int j = lane & 31;
        float o1 = (lane < 32) ? (n1 * cs[j] - other * sn[j])
                               : (other * sn[j] + n1 * cs[j]);
        size_t base = (size_t)t * (NKVH * HD) + wid * HD;
        half_t h;
        h = (half_t)n0; kh[base + lane] = h;
        kl[base + lane] = (half_t)((n0 - (float)h) * 1024.0f);
        h = (half_t)o1; kh[base + 64 + lane] = h;
        kl[base + 64 + lane] = (half_t)((o1 - (float)h) * 1024.0f);
    }
}

// ---------------------------------------------------------------------------
// Chunked flash attention, causal GQA, split-f16 MFMA. 4 waves x 16 q-rows.
// Block = (h, q-block, chunk of <=16 kv-tiles). 1280 near-uniform blocks at
// 2 blocks/CU (VGPR-safe). Single-chunk q-blocks (q<8) write final; others
// write fp32 partials (O-unnorm, m, l) merged by attn_combine.
// ---------------------------------------------------------------------------
__global__ __launch_bounds__(256, 2)
void attn_kernel(const half_t* __restrict__ qh, const half_t* __restrict__ ql,
                 const half_t* __restrict__ kh, const half_t* __restrict__ kl,
                 const half_t* __restrict__ vth, const half_t* __restrict__ vtl,
                 half_t* __restrict__ oh, half_t* __restrict__ ol,
                 float* __restrict__ Op0, float* __restrict__ Op1,
                 float* __restrict__ ml)
{
    const int bid = blockIdx.x;
    const int h = bid & 15, r = bid >> 4;
    int q, c;
    if (r < 8)       { q = r;                 c = 0; }
    else if (r < 24) { q = 8 + ((r - 8) >> 1);  c = (r - 8) & 1; }
    else if (r < 48) { q = 16 + (r - 24) / 3;   c = (r - 24) % 3; }
    else             { q = 24 + ((r - 48) >> 2); c = (r - 48) & 3; }
    const int nch = (q < 8) ? 1 : (q < 16) ? 2 : (q < 24) ? 3 : 4;
    const int kvbeg = c * 512;
    const int kvend = min(kvbeg + 512, q * 64 + 64);

    const int kvh = h >> 2;
    const int tid = threadIdx.x, lane = tid & 63, wid = tid >> 6;
    const int q0 = q * 64 + wid * 16;
    const int l15 = lane & 15, l4 = lane >> 4;

    __shared__ half_t Ksh[32][136], Ksl[32][136];
    __shared__ half_t Vsh[128][40], Vsl[128][40];
    __shared__ half_t Ph[4][16][40], Pl[4][16][40];

    half8 qfh[4], qfl[4];
    {
        const size_t qb = (size_t)(q0 + l15) * (NH * HD) + h * HD + l4 * 8;
#pragma unroll
        for (int cc = 0; cc < 4; ++cc) {
            qfh[cc] = *(const half8*)(qh + qb + cc * 32);
            qfl[cc] = *(const half8*)(ql + qb + cc * 32);
        }
    }

    f32x4 om[8] = {}, oc[8] = {};
    float mrow[4] = { -1e30f, -1e30f, -1e30f, -1e30f };
    float lrow[4] = {};

    const int kr = tid >> 4, kc = (tid & 15) * 8;
    const int vd = tid >> 2, vc = (tid & 3) * 8;
    // NAMED prefetch registers (arrays get demoted to scratch - rule #20)
    uint4 rk0h, rk1h, rk0l, rk1l, rv0h, rv1h, rv0l, rv1l;

#define LOAD_TILE(KV0)                                                        \
    do {                                                                      \
        size_t sk0 = (size_t)((KV0) + kr) * (NKVH * HD) + kvh * HD + kc;      \
        size_t sk1 = sk0 + (size_t)16 * (NKVH * HD);                          \
        rk0h = *(const uint4*)(kh + sk0);  rk0l = *(const uint4*)(kl + sk0);  \
        rk1h = *(const uint4*)(kh + sk1);  rk1l = *(const uint4*)(kl + sk1);  \
        size_t sv0 = (size_t)(kvh * HD + vd) * T_TOK + (KV0) + vc;            \
        size_t sv1 = sv0 + (size_t)64 * T_TOK;                                \
        rv0h = *(const uint4*)(vth + sv0); rv0l = *(const uint4*)(vtl + sv0); \
        rv1h = *(const uint4*)(vth + sv1); rv1l = *(const uint4*)(vtl + sv1); \
    } while (0)

    LOAD_TILE(kvbeg);
    for (int kv0 = kvbeg; kv0 < kvend; kv0 += 32) {
        *(uint4*)&Ksh[kr][kc]      = rk0h;  *(uint4*)&Ksl[kr][kc]      = rk0l;
        *(uint4*)&Ksh[kr + 16][kc] = rk1h;  *(uint4*)&Ksl[kr + 16][kc] = rk1l;
        *(uint4*)&Vsh[vd][vc]      = rv0h;  *(uint4*)&Vsl[vd][vc]      = rv0l;
        *(uint4*)&Vsh[vd + 64][vc] = rv1h;  *(uint4*)&Vsl[vd + 64][vc] = rv1l;
        __syncthreads();
        if (kv0 + 32 < kvend) LOAD_TILE(kv0 + 32);   // overlaps compute

        f32x4 sf[2];
        __builtin_amdgcn_s_setprio(1);
#pragma unroll
        for (int t2 = 0; t2 < 2; ++t2) {       // S = Q K^T (pre-scaled Q)
            f32x4 s = {}, sc = {};
#pragma unroll
            for (int cc = 0; cc < 4; ++cc) {
                half8 bh = *(const half8*)&Ksh[t2 * 16 + l15][cc * 32 + l4 * 8];
                half8 bl = *(const half8*)&Ksl[t2 * 16 + l15][cc * 32 + l4 * 8];
                s  = MFMA16(qfh[cc], bh, s);
                sc = MFMA16(qfh[cc], bl, sc);
                sc = MFMA16(qfl[cc], bh, sc);
            }
            sf[t2] = s + sc * (1.0f / 1024.0f);
        }
        __builtin_amdgcn_s_setprio(0);

        float pmax[4];
#pragma unroll
        for (int i = 0; i < 4; ++i) {
            const int qg = q0 + l4 * 4 + i;
#pragma unroll
            for (int t2 = 0; t2 < 2; ++t2) {
                int kvg = kv0 + t2 * 16 + l15;
                if (kvg > qg) sf[t2][i] = -1e30f;
            }
            float mx = fmaxf(sf[0][i], sf[1][i]);
#pragma unroll
            for (int o = 1; o < 16; o <<= 1) mx = fmaxf(mx, __shfl_xor(mx, o));
            pmax[i] = mx;
        }
        float dm = fmaxf(fmaxf(pmax[0] - mrow[0], pmax[1] - mrow[1]),
                         fmaxf(pmax[2] - mrow[2], pmax[3] - mrow[3]));
        if (__any(dm > 6.0f)) {                // defer-max: rescale rarely
#pragma unroll
            for (int i = 0; i < 4; ++i) {
                float mnew = fmaxf(mrow[i], pmax[i]);
                float resc = expf(mrow[i] - mnew);
                lrow[i] *= resc;
#pragma unroll
                for (int c8 = 0; c8 < 8; ++c8) {
                    om[c8][i] *= resc; oc[c8][i] *= resc;
                }
                mrow[i] = mnew;
            }
        }
#pragma unroll
        for (int i = 0; i < 4; ++i) {
            float p0 = expf(sf[0][i] - mrow[i]);
            float p1 = expf(sf[1][i] - mrow[i]);
            lrow[i] += p0 + p1;
            half_t hh;
            hh = (half_t)p0;
            Ph[wid][l4 * 4 + i][l15] = hh;
            Pl[wid][l4 * 4 + i][l15] = (half_t)((p0 - (float)hh) * 1024.0f);
            hh = (half_t)p1;
            Ph[wid][l4 * 4 + i][16 + l15] = hh;
            Pl[wid][l4 * 4 + i][16 + l15] = (half_t)((p1 - (float)hh) * 1024.0f);
        }

        half8 pah = *(const half8*)&Ph[wid][l15][l4 * 8];
        half8 pal = *(const half8*)&Pl[wid][l15][l4 * 8];
        __builtin_amdgcn_s_setprio(1);
#pragma unroll
        for (int c8 = 0; c8 < 8; ++c8) {       // O += P V
            half8 vh = *(const half8*)&Vsh[c8 * 16 + l15][l4 * 8];
            half8 vl = *(const half8*)&Vsl[c8 * 16 + l15][l4 * 8];
            om[c8] = MFMA16(pah, vh, om[c8]);
            oc[c8] = MFMA16(pah, vl, oc[c8]);
            oc[c8] = MFMA16(pal, vh, oc[c8]);
        }
        __builtin_amdgcn_s_setprio(0);
        __syncthreads();
    }
#undef LOAD_TILE

#pragma unroll
    for (int i = 0; i < 4; ++i)
#pragma unroll
        for (int o = 1; o < 16; o <<= 1) lrow[i] += __shfl_xor(lrow[i], o);

    if (nch == 1) {
#pragma unroll
        for (int c8 = 0; c8 < 8; ++c8) {
#pragma unroll
            for (int i = 0; i < 4; ++i) {
                float v = (om[c8][i] + oc[c8][i] * (1.0f / 1024.0f)) / lrow[i];
                size_t idx = (size_t)(q0 + l4 * 4 + i) * (NH * HD) + h * HD
                           + c8 * 16 + l15;
                half_t hh = (half_t)v;
                oh[idx] = hh;
                ol[idx] = (half_t)((v - (float)hh) * 1024.0f);
            }
        }
    } else {
        float* Op = (bid < 768) ? Op0 + (size_t)bid * 8192
                                : Op1 + (size_t)(bid - 768) * 8192;
#pragma unroll
        for (int c8 = 0; c8 < 8; ++c8) {
#pragma unroll
            for (int i = 0; i < 4; ++i) {
                int row64 = wid * 16 + l4 * 4 + i;
                Op[row64 * 128 + c8 * 16 + l15] =
                    om[c8][i] + oc[c8][i] * (1.0f / 1024.0f);
            }
        }
        if (l15 == 0) {
#pragma unroll
            for (int i = 0; i < 4; ++i) {
                int row64 = wid * 16 + l4 * 4 + i;
                ml[(size_t)bid * 128 + row64]      = mrow[i];
                ml[(size_t)bid * 128 + 64 + row64] = lrow[i];
            }
        }
    }
}

// ---------------------------------------------------------------------------
// Combine partial attention chunks (q >= 8): exact online-softmax merge in
// fp32, write split-f16 attn. Grid 24(q) x 16(h) = 384 blocks.
// ---------------------------------------------------------------------------
__global__ __launch_bounds__(256)
void attn_combine(const float* __restrict__ Op0, const float* __restrict__ Op1,
                  const float* __restrict__ ml,
                  half_t* __restrict__ oh, half_t* __restrict__ ol)
{
    const int bid = blockIdx.x;
    const int h = bid & 15, q = 8 + (bid >> 4);
    const int nch = (q < 16) ? 2 : (q < 24) ? 3 : 4;
    const int r0 = (q < 16) ? 8 + (q - 8) * 2
                 : (q < 24) ? 24 + (q - 16) * 3
                            : 48 + (q - 24) * 4;
    const int tid = threadIdx.x;
    const int row = tid >> 2, cg = (tid & 3) * 32;

    const float* Oc[4];
    float m[4], lv[4];
#pragma unroll
    for (int c = 0; c < 4; ++c) {
        int cc = (c < nch) ? c : nch - 1;
        int slot = (r0 + cc) * 16 + h;
        const float* base = (slot < 768) ? Op0 + (size_t)slot * 8192
                                         : Op1 + (size_t)(slot - 768) * 8192;
        Oc[c] = base + row * 128 + cg;
        m[c]  = ml[(size_t)slot * 128 + row];
        lv[c] = (c < nch) ? ml[(size_t)slot * 128 + 64 + row] : 0.0f;
    }
    float M = fmaxf(fmaxf(m[0], m[1]), fmaxf(m[2], m[3]));
    float w[4], wsum = 0.0f;
#pragma unroll
    for (int c = 0; c < 4; ++c) { w[c] = expf(m[c] - M); wsum += lv[c] * w[c]; }
    float inv = 1.0f / wsum;
    float wO[4];
#pragma unroll
    for (int c = 0; c < 4; ++c) wO[c] = (c < nch) ? w[c] * inv : 0.0f;

    size_t obase = (size_t)(q * 64 + row) * (NH * HD) + h * HD + cg;
#pragma unroll
    for (int jj = 0; jj < 4; ++jj) {
        floatx4 a0 = {0,0,0,0}, a1 = {0,0,0,0};
#pragma unroll
        for (int c = 0; c < 4; ++c) {
            floatx4 v0 = *(const floatx4*)(Oc[c] + jj * 8);
            floatx4 v1 = *(const floatx4*)(Oc[c] + jj * 8 + 4);
            a0 += wO[c] * v0;
            a1 += wO[c] * v1;
        }
        half8 hv, lvv;
#pragma unroll
        for (int k = 0; k < 4; ++k) {
            half_t hh = (half_t)a0[k];
            hv[k] = hh; lvv[k] = (half_t)((a0[k] - (float)hh) * 1024.0f);
            hh = (half_t)a1[k];
            hv[4 + k] = hh; lvv[4 + k] = (half_t)((a1[k] - (float)hh) * 1024.0f);
        }
        *(half8*)(oh + obase + jj * 8) = hv;
        *(half8*)(ol + obase + jj * 8) = lvv;
    }
}

// ---------------------------------------------------------------------------
// Linear router: logit_e = rs(x2) * ( x.u_e + attn_precise . ow_u_e ).
// ---------------------------------------------------------------------------
__global__ __launch_bounds__(256)
void router_linear(const float* __restrict__ x, const half_t* __restrict__ ah,
                   const half_t* __restrict__ al, const float* __restrict__ x2,
                   const float* __restrict__ ln2w, const float* __restrict__ rw,
                   const float* __restrict__ owu, float* __restrict__ combine)
{
    const int t = blockIdx.x, tid = threadIdx.x;
    const float* xr2 = x2 + (size_t)t * HIDN;
    float ss = 0.0f;
#pragma unroll
    for (int i = 0; i < 8; ++i) {
        float v = xr2[tid + i * 256];
        ss += v * v;
    }
    for (int o = 32; o; o >>= 1) ss += __shfl_down(ss, o);
    __shared__ float red[4];
    if ((tid & 63) == 0) red[tid >> 6] = ss;
    __syncthreads();
    ss = red[0] + red[1] + red[2] + red[3];
    float rs = rsqrtf(ss * (1.0f / HIDN) + 1e-6f);

    const float* xr = x + (size_t)t * HIDN;
    const half_t* ar = ah + (size_t)t * HIDN;
    const half_t* alr = al + (size_t)t * HIDN;
    float acc[NEXP] = {};
#pragma unroll
    for (int i = 0; i < 8; ++i) {
        int c = tid + i * 256;
        float xv = xr[c] * ln2w[c];
        float ap = (float)ar[c] + (float)alr[c] * (1.0f / 1024.0f);
        const float* rwc = rw + (size_t)c * NEXP;
        const float* owc = owu + (size_t)c * NEXP;
#pragma unroll
        for (int e = 0; e < NEXP; ++e) acc[e] += xv * rwc[e] + ap * owc[e];
    }
#pragma unroll
    for (int e = 0; e < NEXP; ++e)
        for (int o = 32; o; o >>= 1) acc[e] += __shfl_down(acc[e], o);
    __shared__ float red8[4][NEXP];
    if ((tid & 63) == 0)
#pragma unroll
        for (int e = 0; e < NEXP; ++e) red8[tid >> 6][e] = acc[e];
    __syncthreads();
    if (tid == 0) {
        float lg[NEXP];
#pragma unroll
        for (int e = 0; e < NEXP; ++e)
            lg[e] = (red8[0][e] + red8[1][e] + red8[2][e] + red8[3][e]) * rs;
        int i1 = 0;
        for (int e = 1; e < NEXP; ++e) if (lg[e] > lg[i1]) i1 = e;
        int i2 = (i1 == 0) ? 1 : 0;
        for (int e = 0; e < NEXP; ++e) if (e != i1 && lg[e] > lg[i2]) i2 = e;
        float mx = lg[i1];
        float p1 = expf(lg[i1] - mx), p2 = expf(lg[i2] - mx);
        float inv = 1.0f / (p1 + p2);
        float* cr = combine + (size_t)t * NEXP;
#pragma unroll
        for (int e = 0; e < NEXP; ++e) cr[e] = 0.0f;
        cr[i1] = p1 * inv;
        cr[i2] = p2 * inv;
    }
}

// ---------------------------------------------------------------------------
// MoE activation: Abig[t][n] = scale * silu(G[t][n]) * U[t][n]
// ---------------------------------------------------------------------------
__global__ __launch_bounds__(256)
void moe_act(const half_t* __restrict__ GU, const float* __restrict__ comb,
             half_t* __restrict__ Abig)
{
    int idx = blockIdx.x * 256 + threadIdx.x;
    int t = idx / 640, c8 = idx % 640;
    int n = c8 * 8;
    half8 g8 = *(const half8*)(GU + (size_t)t * 10240 + n);
    half8 u8 = *(const half8*)(GU + (size_t)t * 10240 + 5120 + n);
    float sc = (n < 1024) ? 1.0f : comb[(size_t)t * NEXP + ((n - 1024) >> 9)];
    half8 o8;
#pragma unroll
    for (int j = 0; j < 8; ++j) {
        float g = (float)g8[j], u = (float)u8[j];
        float s = g / (1.0f + expf(-g));
        o8[j] = (half_t)(s * u * sc);
    }
    *(half8*)(Abig + (size_t)t * 5120 + n) = o8;
}

// ---------------------------------------------------------------------------
extern "C" void kernel_launch(void* const* d_in, const int* in_sizes, int n_in,
                              void* d_out, int out_size, void* d_ws, size_t ws_size,
                              hipStream_t stream)
{
    (void)in_sizes; (void)n_in; (void)out_size; (void)ws_size;
    const float* x    = (const float*)d_in[0];
    const int*   pos  = (const int*)  d_in[1];
    const float* ln1w = (const float*)d_in[2];
    const float* qkvw = (const float*)d_in[3];
    const float* qkvb = (const float*)d_in[4];
    const float* klnw = (const float*)d_in[5];
    const float* ow   = (const float*)d_in[6];
    const float* ln2w = (const float*)d_in[7];
    const float* rw   = (const float*)d_in[8];
    const float* w1   = (const float*)d_in[9];
    const float* w2   = (const float*)d_in[10];
    const float* w3   = (const float*)d_in[11];
    const float* sw1  = (const float*)d_in[12];
    const float* sw2  = (const float*)d_in[13];
    const float* sw3  = (const float*)d_in[14];
    float* out = (float*)d_out;

    // ---- workspace arena (phase-overlapped; total 142,671,872 B) ----
    char* ws = (char*)d_ws;
    const size_t AB = 16842752;
    float*  x2      = (float*)(ws);                   // also Opart1 (512 slots)
    float*  combine = (float*)(ws + 16777216);
    half_t* h_hi    = (half_t*)(ws + AB);
    half_t* h_lo    = (half_t*)(ws + AB + 8388608);
    half_t* qkvwt_h = (half_t*)(ws + AB + 16777216);
    half_t* qkvwt_l = (half_t*)(ws + AB + 29360128);
    float*  qkv     = (float*)(ws + AB + 41943040);   // also Opart0 (768 slots)
    half_t* q_h     = (half_t*)(ws + AB + 67108864);
    half_t* q_l     = (half_t*)(ws + AB + 75497472);
    half_t* k_h     = (half_t*)(ws + AB + 83886080);
    half_t* k_l     = (half_t*)(ws + AB + 85983232);
    half_t* vt_h    = (half_t*)(ws + AB + 88080384);
    half_t* vt_l    = (half_t*)(ws + AB + 90177536);
    half_t* attn_h  = (half_t*)(ws + AB);             // reuse h_hi
    half_t* attn_l  = (half_t*)(ws + AB + 8388608);   // reuse h_lo
    half_t* owt     = (half_t*)(ws + AB + 16777216);  // reuse qkvwt_h
    float*  ow_u    = (float*)(ws + AB + 25165824);   // 64 KB
    float*  mlpart  = (float*)(ws + AB + 25231360);   // 656 KB (dead region)
    float*  Opart0  = (float*)(ws + AB + 41943040);   // = qkv region (25.2MB)
    float*  Opart1  = (float*)(ws);                   // = x2 region (16.8MB)
    half_t* h2      = (half_t*)(ws + AB + 33554432);
    half_t* W13t    = (half_t*)(ws + AB + 41943040);  // reuse qkv + q (dead)
    half_t* GU      = (half_t*)(ws + AB + 83886080);  // reuse k/vt (dead)
    half_t* Abig    = (half_t*)(ws + AB);             // reuse attn (dead)
    half_t* W2t     = (half_t*)(ws + AB + 41943040);  // reuse W13t (dead)

    dim3 b256(256);

    // 1. h = rmsnorm(x, ln1_w) split
    rmsnorm_split_k<<<T_TOK, b256, 0, stream>>>(x, ln1w, h_hi, h_lo);
    // 2. qkv_w -> transposed split f16
    transpose_split2<<<dim3(QKV_N / 32, HIDN / 32), b256, 0, stream>>>(
        qkvw, qkvwt_h, qkvwt_l, QKV_N, HIDN);
    // 3. qkv = h @ qkv_w + b   (split path)
    gemm_f16<true, 64><<<dim3(QKV_N / 128, T_TOK / 64), b256, 0, stream>>>(
        h_hi, h_lo, qkvwt_h, qkvwt_l, qkvb, nullptr, qkv, nullptr,
        T_TOK, QKV_N, HIDN);
    // 4. k-rmsnorm + rope + split (q pre-scaled)
    qkv_prep<<<T_TOK, b256, 0, stream>>>(qkv, pos, klnw, q_h, q_l, k_h, k_l);
    // 5. v^T: vt[d][t] = qkv[t][2560+d] (split)
    transpose_split2<<<dim3(512 / 32, T_TOK / 32), b256, 0, stream>>>(
        qkv + 2560, vt_h, vt_l, QKV_N, T_TOK);
    // 6. o_w transpose (single f16)
    transpose_f16<<<dim3(HIDN / 64, HIDN / 32), b256, 0, stream>>>(
        ow, owt, HIDN, HIDN);
    // 7. ow_u = o_w @ (ln2w * rw)   (fp32 router projection)
    owu_kernel<<<512, b256, 0, stream>>>(ow, ln2w, rw, ow_u);
    // 8. attention (chunked KV, 1280 uniform blocks, 2/CU)
    attn_kernel<<<1280, b256, 0, stream>>>(
        q_h, q_l, k_h, k_l, vt_h, vt_l, attn_h, attn_l,
        Opart0, Opart1, mlpart);
    // 8b. combine partial chunks (q >= 8)
    attn_combine<<<384, b256, 0, stream>>>(Opart0, Opart1, mlpart,
                                           attn_h, attn_l);
    // 9. x2 = x + attn @ o_w   (single f16; router bypasses this)
    gemm_f16<false, 64><<<dim3(HIDN / 128, T_TOK / 64), b256, 0, stream>>>(
        attn_h, nullptr, owt, nullptr, nullptr, x, x2, nullptr,
        T_TOK, HIDN, HIDN);
    // 10. router (exact linear path) -> combine weights
    router_linear<<<T_TOK, b256, 0, stream>>>(
        x, attn_h, attn_l, x2, ln2w, rw, ow_u, combine);
    // 11. h2 = rmsnorm(x2, ln2_w), single f16
    rmsnorm_split_k<<<T_TOK, b256, 0, stream>>>(x2, ln2w, h2, nullptr);
    // 12. W13t batched transpose (1 launch)
    w13_transpose<<<dim3(10240 / 64, HIDN / 32), b256, 0, stream>>>(
        sw1, w1, sw3, w3, W13t);
    // 13. GU = h2 @ [W1|W3]  (single f16, f16 out)
    gemm_f16<false, 128><<<dim3(10240 / 128, T_TOK / 128), b256, 0, stream>>>(
        h2, nullptr, W13t, nullptr, nullptr, nullptr, nullptr, GU,
        T_TOK, 10240, HIDN);
    // 14. W2t batched transpose (1 launch)
    w2_transpose<<<dim3(HIDN / 64, 5120 / 32), b256, 0, stream>>>(sw2, w2, W2t);
    // 15. Abig = combine-scaled silu(G)*U
    moe_act<<<(T_TOK * 640) / 256, b256, 0, stream>>>(GU, combine, Abig);
    // 16. out = x2 + Abig @ W2cat
    gemm_f16<false, 64><<<dim3(HIDN / 128, T_TOK / 64), b256, 0, stream>>>(
        Abig, nullptr, W2t, nullptr, nullptr, x2, out, nullptr,
        T_TOK, HIDN, 5120);
}

// Round 7
// 622.249 us; speedup vs baseline: 1.1641x; 1.0456x over previous
//
#include <hip/hip_runtime.h>

// ---------------------------------------------------------------------------
// PanguProMoE decoder layer, MI355X (gfx950).
// Precision: qkv GEMM + attention in split-f16 ("f16x2": x = hi + lo/1024,
// 3 MFMAs/tile). Router logits via exact linear path (router_linear).
// R7: TOP-2 SPARSE MoE. Router emits top-2 idx/weights; device-side
// histogram + 64-aligned scan + scatter builds per-expert pair lists;
// grouped GU GEMM gathers A-rows per-lane via pairTok (global_load_lds has
// per-lane global src); grouped act applies pair weight; grouped down GEMM
// -> Ypair; out[t] = (x2 + sharedDown)[t] + Ypair[p1]+Ypair[p2].
// Expert GEMM work 103->29 GF. Shared expert dense (W13t relayout: shared
// gate|up rows 0..2047 -> single N=2048 GEMM). Attn chunks rebalanced evenly.
// All MFMA kernels at min-waves/EU=2 (R5: 3 caps VGPR at 85 -> spill).
// ---------------------------------------------------------------------------

typedef _Float16 half_t;
typedef _Float16 half8 __attribute__((ext_vector_type(8)));
typedef float    f32x4 __attribute__((ext_vector_type(4)));
typedef float    floatx4 __attribute__((ext_vector_type(4)));

#define T_TOK 2048
#define HIDN  2048
#define NH    16
#define NKVH  4
#define HD    128
#define QKV_N 3072
#define NEXP  8
#define NPAIR_MAX 4608   // 4096 pairs + 8*63 padding, 64-aligned

#define MFMA16(a,b,c) __builtin_amdgcn_mfma_f32_16x16x32_f16(a,b,c,0,0,0)

__device__ __forceinline__ void gload_lds16(const half_t* g, half_t* l) {
    __builtin_amdgcn_global_load_lds(
        (const __attribute__((address_space(1))) void*)g,
        (__attribute__((address_space(3))) void*)l, 16, 0, 0);
}

__device__ __forceinline__ float silu_f(float g) {
    return g / (1.0f + expf(-g));
}

// ---------------------------------------------------------------------------
// rmsnorm over HIDN cols, write split f16 (lo optional)
// ---------------------------------------------------------------------------
__global__ __launch_bounds__(256)
void rmsnorm_split_k(const float* __restrict__ x, const float* __restrict__ w,
                     half_t* __restrict__ hi, half_t* __restrict__ lo)
{
    const int row = blockIdx.x, tid = threadIdx.x;
    const float* xr = x + (size_t)row * HIDN;
    floatx4 v0 = *(const floatx4*)(xr + tid * 8);
    floatx4 v1 = *(const floatx4*)(xr + tid * 8 + 4);
    float ss = v0[0]*v0[0] + v0[1]*v0[1] + v0[2]*v0[2] + v0[3]*v0[3]
             + v1[0]*v1[0] + v1[1]*v1[1] + v1[2]*v1[2] + v1[3]*v1[3];
    for (int o = 32; o; o >>= 1) ss += __shfl_down(ss, o);
    __shared__ float red[4];
    if ((tid & 63) == 0) red[tid >> 6] = ss;
    __syncthreads();
    ss = red[0] + red[1] + red[2] + red[3];
    float rs = rsqrtf(ss * (1.0f / HIDN) + 1e-6f);
    floatx4 w0 = *(const floatx4*)(w + tid * 8);
    floatx4 w1 = *(const floatx4*)(w + tid * 8 + 4);
    float vv[8] = { v0[0]*w0[0], v0[1]*w0[1], v0[2]*w0[2], v0[3]*w0[3],
                    v1[0]*w1[0], v1[1]*w1[1], v1[2]*w1[2], v1[3]*w1[3] };
    half8 hv, lv;
#pragma unroll
    for (int j = 0; j < 8; ++j) {
        float o = vv[j] * rs;
        half_t h = (half_t)o;
        hv[j] = h;
        lv[j] = (half_t)((o - (float)h) * 1024.0f);
    }
    *(half8*)(hi + (size_t)row * HIDN + tid * 8) = hv;
    if (lo) *(half8*)(lo + (size_t)row * HIDN + tid * 8) = lv;
}

// ---------------------------------------------------------------------------
// Transpose fp32 -> split f16: dst[n][k] = src[k][n]. 32x32 tile.
// ---------------------------------------------------------------------------
__global__ __launch_bounds__(256)
void transpose_split2(const float* __restrict__ src, half_t* __restrict__ dh,
                      half_t* __restrict__ dl, int sstride, int dstride)
{
    __shared__ float tile[32][36];
    const int n0 = blockIdx.x * 32, k0 = blockIdx.y * 32;
    const int tid = threadIdx.x;
    {
        int r = tid >> 3, c = (tid & 7) * 4;
        *(floatx4*)&tile[r][c] =
            *(const floatx4*)(src + (size_t)(k0 + r) * sstride + n0 + c);
    }
    __syncthreads();
    int n = tid & 31, g = tid >> 5, gg = g & 3;
    half8 hv;
    if (g < 4) {
#pragma unroll
        for (int j = 0; j < 8; ++j) hv[j] = (half_t)tile[gg * 8 + j][n];
        *(half8*)(dh + (size_t)(n0 + n) * dstride + k0 + gg * 8) = hv;
    } else {
#pragma unroll
        for (int j = 0; j < 8; ++j) {
            float v = tile[gg * 8 + j][n];
            half_t h = (half_t)v;
            hv[j] = (half_t)((v - (float)h) * 1024.0f);
        }
        *(half8*)(dl + (size_t)(n0 + n) * dstride + k0 + gg * 8) = hv;
    }
}

// ---------------------------------------------------------------------------
// Transpose fp32 -> single f16: dst[n][k] = src[k][n]. 32(k)x64(n) tile.
// ---------------------------------------------------------------------------
__global__ __launch_bounds__(256)
void transpose_f16(const float* __restrict__ src, half_t* __restrict__ dh,
                   int sstride, int dstride)
{
    __shared__ float tile[32][68];
    const int n0 = blockIdx.x * 64, k0 = blockIdx.y * 32;
    const int tid = threadIdx.x;
    {
        int r = tid >> 3, c = (tid & 7) * 4;
        const float* s = src + (size_t)(k0 + r) * sstride + n0;
        *(floatx4*)&tile[r][c]      = *(const floatx4*)(s + c);
        *(floatx4*)&tile[r][c + 32] = *(const floatx4*)(s + c + 32);
    }
    __syncthreads();
    int n = tid & 63, g = tid >> 6;
    half8 hv;
#pragma unroll
    for (int j = 0; j < 8; ++j) hv[j] = (half_t)tile[g * 8 + j][n];
    *(half8*)(dh + (size_t)(n0 + n) * dstride + k0 + g * 8) = hv;
}

// ---------------------------------------------------------------------------
// Batched W13 transpose, NEW layout: W13t[n][k], n<10240:
//  [0,1024): sw1 | [1024,2048): sw3 | [2048,6144): w1[e] | [6144,10240): w3[e]
// (shared gate|up contiguous -> single dense N=2048 shared GU GEMM)
// ---------------------------------------------------------------------------
__global__ __launch_bounds__(256)
void w13_transpose(const float* __restrict__ sw1, const float* __restrict__ w1,
                   const float* __restrict__ sw3, const float* __restrict__ w3,
                   half_t* __restrict__ dst)
{
    __shared__ float tile[32][68];
    const int n0 = blockIdx.x * 64, k0 = blockIdx.y * 32;
    const int tid = threadIdx.x;
    const float* base;
    int stride;
    if (n0 < 1024)      { base = sw1 + n0; stride = 1024; }
    else if (n0 < 2048) { base = sw3 + (n0 - 1024); stride = 1024; }
    else if (n0 < 6144) { int e = (n0 - 2048) >> 9;
                          base = w1 + (size_t)e * HIDN * 512 + ((n0 - 2048) & 511);
                          stride = 512; }
    else                { int e = (n0 - 6144) >> 9;
                          base = w3 + (size_t)e * HIDN * 512 + ((n0 - 6144) & 511);
                          stride = 512; }
    {
        int r = tid >> 3, c = (tid & 7) * 4;
        const float* s = base + (size_t)(k0 + r) * stride;
        *(floatx4*)&tile[r][c]      = *(const floatx4*)(s + c);
        *(floatx4*)&tile[r][c + 32] = *(const floatx4*)(s + c + 32);
    }
    __syncthreads();
    int n = tid & 63, g = tid >> 6;
    half8 hv;
#pragma unroll
    for (int j = 0; j < 8; ++j) hv[j] = (half_t)tile[g * 8 + j][n];
    *(half8*)(dst + (size_t)(n0 + n) * HIDN + k0 + g * 8) = hv;
}

// ---------------------------------------------------------------------------
// Batched W2 transpose: W2t[n][k] (n<2048, k<5120), f16, dstride 5120.
// k<1024: sw2 ; else w2[e][(k-1024)&511].
// ---------------------------------------------------------------------------
__global__ __launch_bounds__(256)
void w2_transpose(const float* __restrict__ sw2, const float* __restrict__ w2,
                  half_t* __restrict__ dst)
{
    __shared__ float tile[32][68];
    const int n0 = blockIdx.x * 64, k0 = blockIdx.y * 32;
    const int tid = threadIdx.x;
    {
        int r = tid >> 3, c = (tid & 7) * 4;
        int k = k0 + r;
        const float* s;
        if (k < 1024) s = sw2 + (size_t)k * HIDN + n0;
        else {
            int e = (k - 1024) >> 9, kk = (k - 1024) & 511;
            s = w2 + ((size_t)e * 512 + kk) * HIDN + n0;
        }
        *(floatx4*)&tile[r][c]      = *(const floatx4*)(s + c);
        *(floatx4*)&tile[r][c + 32] = *(const floatx4*)(s + c + 32);
    }
    __syncthreads();
    int n = tid & 63, g = tid >> 6;
    half8 hv;
#pragma unroll
    for (int j = 0; j < 8; ++j) hv[j] = (half_t)tile[g * 8 + j][n];
    *(half8*)(dst + (size_t)(n0 + n) * 5120 + k0 + g * 8) = hv;
}

// ---------------------------------------------------------------------------
// ow_u[k][e] = sum_c o_w[k][c] * ln2w[c] * rw[c][e]   (fp32, 2048x8)
// ---------------------------------------------------------------------------
__global__ __launch_bounds__(256)
void owu_kernel(const float* __restrict__ ow, const float* __restrict__ ln2w,
                const float* __restrict__ rw, float* __restrict__ owu)
{
    const int k = blockIdx.x * 4 + (threadIdx.x >> 6);
    const int lane = threadIdx.x & 63;
    float acc[NEXP] = {};
    const float* row = ow + (size_t)k * HIDN;
#pragma unroll
    for (int j = 0; j < 8; ++j) {
        int c = j * 256 + lane * 4;
        floatx4 ov = *(const floatx4*)(row + c);
        floatx4 lw = *(const floatx4*)(ln2w + c);
#pragma unroll
        for (int i = 0; i < 4; ++i) {
            float s = ov[i] * lw[i];
            const float* rwc = rw + (size_t)(c + i) * NEXP;
#pragma unroll
            for (int e = 0; e < NEXP; ++e) acc[e] += s * rwc[e];
        }
    }
#pragma unroll
    for (int e = 0; e < NEXP; ++e)
        for (int o = 32; o; o >>= 1) acc[e] += __shfl_down(acc[e], o);
    if (lane == 0) {
#pragma unroll
        for (int e = 0; e < NEXP; ++e) owu[(size_t)k * NEXP + e] = acc[e];
    }
}

// ---------------------------------------------------------------------------
// GEMM: C[M][N] = A[M][K] @ Bt[N][K]^T (+bias)(+res). f16 in, fp32 acc.
// SPLIT: (hi, lo*1024) pairs, 3 MFMAs/tile. BM x 128 tile, BK=32, 4 waves.
// 2-phase double-buffer. ldb = B row stride (>=K).
// ---------------------------------------------------------------------------
template<bool SPLIT, int BM>
__global__ __launch_bounds__(256, 2)
void gemm_f16(const half_t* __restrict__ Ah, const half_t* __restrict__ Al,
              const half_t* __restrict__ Bth, const half_t* __restrict__ Btl,
              const float* __restrict__ bias, const float* __restrict__ res,
              float* __restrict__ Cf, half_t* __restrict__ Ch,
              int M, int N, int K, int ldb)
{
    constexpr int NBUF = SPLIT ? 2 : 1;
    constexpr int MR = BM / 32;
    __shared__ half_t As[2][NBUF][BM * 32];
    __shared__ half_t Bs[2][NBUF][128 * 32];
    const int tid = threadIdx.x, lane = tid & 63, wid = tid >> 6;
    const int l15 = lane & 15, l4 = lane >> 4;
    const int row0 = blockIdx.y * BM, col0 = blockIdx.x * 128;
    const int wr = (wid >> 1) * (BM / 2), wc = (wid & 1) * 64;
    f32x4 accM[MR][4] = {}, accC[MR][4] = {};
    const int lrw = lane >> 2, lcl = (lane & 3) * 8;

#define STAGE(BUF, K0)                                                        \
    do {                                                                      \
        _Pragma("unroll")                                                     \
        for (int j = 0; j < BM / 64; ++j) {                                   \
            const int r = wid * (BM / 4) + j * 16;                            \
            const size_t ga = (size_t)(row0 + r + lrw) * K + (K0) + lcl;      \
            gload_lds16(Ah + ga, &As[BUF][0][r * 32]);                        \
            if constexpr (SPLIT) gload_lds16(Al + ga, &As[BUF][1][r * 32]);   \
        }                                                                     \
        _Pragma("unroll")                                                     \
        for (int j = 0; j < 2; ++j) {                                         \
            const int r = wid * 32 + j * 16;                                  \
            const size_t gb = (size_t)(col0 + r + lrw) * ldb + (K0) + lcl;    \
            gload_lds16(Bth + gb, &Bs[BUF][0][r * 32]);                       \
            if constexpr (SPLIT) gload_lds16(Btl + gb, &Bs[BUF][1][r * 32]);  \
        }                                                                     \
    } while (0)

    STAGE(0, 0);
    __syncthreads();
    int cur = 0;
    for (int k0 = 0; k0 < K; k0 += 32, cur ^= 1) {
        if (k0 + 32 < K) STAGE(cur ^ 1, k0 + 32);
        half8 ah[MR], al[MR], bh[4], bl[4];
#pragma unroll
        for (int m = 0; m < MR; ++m) {
            int off = (wr + m * 16 + l15) * 32 + l4 * 8;
            ah[m] = *(const half8*)&As[cur][0][off];
            if constexpr (SPLIT) al[m] = *(const half8*)&As[cur][1][off];
        }
#pragma unroll
        for (int n = 0; n < 4; ++n) {
            int off = (wc + n * 16 + l15) * 32 + l4 * 8;
            bh[n] = *(const half8*)&Bs[cur][0][off];
            if constexpr (SPLIT) bl[n] = *(const half8*)&Bs[cur][1][off];
        }
#pragma unroll
        for (int m = 0; m < MR; ++m)
#pragma unroll
            for (int n = 0; n < 4; ++n) {
                accM[m][n] = MFMA16(ah[m], bh[n], accM[m][n]);
                if constexpr (SPLIT) {
                    accC[m][n] = MFMA16(ah[m], bl[n], accC[m][n]);
                    accC[m][n] = MFMA16(al[m], bh[n], accC[m][n]);
                }
            }
        __syncthreads();
    }
#undef STAGE

#pragma unroll
    for (int m = 0; m < MR; ++m) {
#pragma unroll
        for (int n = 0; n < 4; ++n) {
            int gr0 = row0 + wr + m * 16 + l4 * 4;
            int gc  = col0 + wc + n * 16 + l15;
            float b = bias ? bias[gc] : 0.0f;
#pragma unroll
            for (int i = 0; i < 4; ++i) {
                float v = accM[m][n][i];
                if constexpr (SPLIT) v += accC[m][n][i] * (1.0f / 1024.0f);
                v += b;
                size_t idx = (size_t)(gr0 + i) * N + gc;
                if (res) v += res[idx];
                if (Cf) Cf[idx] = v;
                if (Ch) Ch[idx] = (half_t)v;
            }
        }
    }
}

// ---------------------------------------------------------------------------
// Grouped GU GEMM (experts): rows = pair slots (64-aligned per expert),
// A row p = h2[pairTok[p]] (per-lane global gather via global_load_lds),
// B = W13t expert slice (gate 2048+512e, up 6144+512e). Out GUp[p][1024].
// Grid (8 col-tiles, 72 row-tiles). K=2048.
// ---------------------------------------------------------------------------
__global__ __launch_bounds__(256, 2)
void gemm_grouped_gu(const half_t* __restrict__ h2, const half_t* __restrict__ W13t,
                     const int* __restrict__ pairTok, const int* __restrict__ basep,
                     half_t* __restrict__ GUp)
{
    __shared__ half_t As[2][64 * 32];
    __shared__ half_t Bs[2][128 * 32];
    const int tid = threadIdx.x, lane = tid & 63, wid = tid >> 6;
    const int l15 = lane & 15, l4 = lane >> 4;
    const int lrw = lane >> 2, lcl = (lane & 3) * 8;
    const int row0 = blockIdx.y * 64, ct = blockIdx.x;
    int e = 0;
#pragma unroll
    for (int i = 1; i < NEXP; ++i) if (row0 >= basep[i]) e = i;
    const int brow0 = (ct < 4) ? (2048 + 512 * e + ct * 128)
                               : (6144 + 512 * e + (ct - 4) * 128);
    const int wr = (wid >> 1) * 32, wc = (wid & 1) * 64;
    const int tok = pairTok[row0 + wid * 16 + lrw];   // per-lane A row token
    const half_t* Abase = h2 + (size_t)tok * HIDN + lcl;
    f32x4 acc[2][4] = {};

#define GSTAGE(BUF, K0)                                                       \
    do {                                                                      \
        gload_lds16(Abase + (K0), &As[BUF][(wid * 16) * 32]);                 \
        _Pragma("unroll")                                                     \
        for (int j = 0; j < 2; ++j) {                                         \
            const int r = wid * 32 + j * 16;                                  \
            const size_t gb = (size_t)(brow0 + r + lrw) * HIDN + (K0) + lcl;  \
            gload_lds16(W13t + gb, &Bs[BUF][r * 32]);                         \
        }                                                                     \
    } while (0)

    GSTAGE(0, 0);
    __syncthreads();
    int cur = 0;
    for (int k0 = 0; k0 < HIDN; k0 += 32, cur ^= 1) {
        if (k0 + 32 < HIDN) GSTAGE(cur ^ 1, k0 + 32);
        half8 ah[2], bh[4];
#pragma unroll
        for (int m = 0; m < 2; ++m)
            ah[m] = *(const half8*)&As[cur][(wr + m * 16 + l15) * 32 + l4 * 8];
#pragma unroll
        for (int n = 0; n < 4; ++n)
            bh[n] = *(const half8*)&Bs[cur][(wc + n * 16 + l15) * 32 + l4 * 8];
#pragma unroll
        for (int m = 0; m < 2; ++m)
#pragma unroll
            for (int n = 0; n < 4; ++n)
                acc[m][n] = MFMA16(ah[m], bh[n], acc[m][n]);
        __syncthreads();
    }
#undef GSTAGE

#pragma unroll
    for (int m = 0; m < 2; ++m)
#pragma unroll
        for (int n = 0; n < 4; ++n) {
            int gr0 = row0 + wr + m * 16 + l4 * 4;
            int gc  = ct * 128 + wc + n * 16 + l15;
#pragma unroll
            for (int i = 0; i < 4; ++i)
                GUp[(size_t)(gr0 + i) * 1024 + gc] = (half_t)acc[m][n][i];
        }
}

// ---------------------------------------------------------------------------
// Grouped down GEMM (experts): Ypair[p][2048] = Ab[p][512] @ W2e^T.
// B rows = W2t[n][1024+512e + kk], ldb=5120. Grid (16 col-tiles, 72 row-tiles).
// ---------------------------------------------------------------------------
__global__ __launch_bounds__(256, 2)
void gemm_grouped_down(const half_t* __restrict__ Ab, const half_t* __restrict__ W2t,
                       const int* __restrict__ basep, half_t* __restrict__ Ypair)
{
    __shared__ half_t As[2][64 * 32];
    __shared__ half_t Bs[2][128 * 32];
    const int tid = threadIdx.x, lane = tid & 63, wid = tid >> 6;
    const int l15 = lane & 15, l4 = lane >> 4;
    const int lrw = lane >> 2, lcl = (lane & 3) * 8;
    const int row0 = blockIdx.y * 64, col0 = blockIdx.x * 128;
    int e = 0;
#pragma unroll
    for (int i = 1; i < NEXP; ++i) if (row0 >= basep[i]) e = i;
    const int bcol = 1024 + 512 * e;
    const int wr = (wid >> 1) * 32, wc = (wid & 1) * 64;
    f32x4 acc[2][4] = {};

#define DSTAGE(BUF, K0)                                                       \
    do {                                                                      \
        const size_t ga = (size_t)(row0 + wid * 16 + lrw) * 512 + (K0) + lcl; \
        gload_lds16(Ab + ga, &As[BUF][(wid * 16) * 32]);                      \
        _Pragma("unroll")                                                     \
        for (int j = 0; j < 2; ++j) {                                         \
            const int r = wid * 32 + j * 16;                                  \
            const size_t gb = (size_t)(col0 + r + lrw) * 5120 + bcol + (K0) + lcl; \
            gload_lds16(W2t + gb, &Bs[BUF][r * 32]);                          \
        }                                                                     \
    } while (0)

    DSTAGE(0, 0);
    __syncthreads();
    int cur = 0;
    for (int k0 = 0; k0 < 512; k0 += 32, cur ^= 1) {
        if (k0 + 32 < 512) DSTAGE(cur ^ 1, k0 + 32);
        half8 ah[2], bh[4];
#pragma unroll
        for (int m = 0; m < 2; ++m)
            ah[m] = *(const half8*)&As[cur][(wr + m * 16 + l15) * 32 + l4 * 8];
#pragma unroll
        for (int n = 0; n < 4; ++n)
            bh[n] = *(const half8*)&Bs[cur][(wc + n * 16 + l15) * 32 + l4 * 8];
#pragma unroll
        for (int m = 0; m < 2; ++m)
#pragma unroll
            for (int n = 0; n < 4; ++n)
                acc[m][n] = MFMA16(ah[m], bh[n], acc[m][n]);
        __syncthreads();
    }
#undef DSTAGE

#pragma unroll
    for (int m = 0; m < 2; ++m)
#pragma unroll
        for (int n = 0; n < 4; ++n) {
            int gr0 = row0 + wr + m * 16 + l4 * 4;
            int gc  = col0 + wc + n * 16 + l15;
#pragma unroll
            for (int i = 0; i < 4; ++i)
                Ypair[(size_t)(gr0 + i) * HIDN + gc] = (half_t)acc[m][n][i];
        }
}

// ---------------------------------------------------------------------------
// qkv post-processing: k-rmsnorm, RoPE on q/k, Q pre-scaled, split-f16 out.
// ---------------------------------------------------------------------------
__global__ __launch_bounds__(256)
void qkv_prep(const float* __restrict__ qkv, const int* __restrict__ pos,
              const float* __restrict__ klnw,
              half_t* __restrict__ qh, half_t* __restrict__ ql,
              half_t* __restrict__ kh, half_t* __restrict__ kl)
{
    const int t = blockIdx.x, tid = threadIdx.x, lane = tid & 63, wid = tid >> 6;
    const float* row = qkv + (size_t)t * QKV_N;
    __shared__ float cs[32], sn[32];
    if (tid < 32) {
        double freq = exp((double)tid * -0.28782313662425572);  // -ln(1e4)/32
        double ang = (double)pos[t] * freq;
        const double twopi = 6.283185307179586476925286766559;
        ang -= twopi * floor(ang * (1.0 / twopi));
        float a = (float)ang;
        cs[tid] = cosf(a);
        sn[tid] = sinf(a);
    }
    __syncthreads();

    const float qscale = 0.08838834764831845f;   // 128^-0.5
    {
        const int hh = tid >> 4, d0 = (tid & 15) * 8;
        const float* qrow = row + hh * HD;
        float outv[8];
        if (d0 < 64) {
#pragma unroll
            for (int j = 0; j < 8; ++j) outv[j] = qrow[d0 + j];
        } else if (d0 < 96) {
            int j0 = d0 - 64;
#pragma unroll
            for (int j = 0; j < 8; ++j) {
                int jj = j0 + j;
                outv[j] = qrow[64 + jj] * cs[jj] - qrow[96 + jj] * sn[jj];
            }
        } else {
            int j0 = d0 - 96;
#pragma unroll
            for (int j = 0; j < 8; ++j) {
                int jj = j0 + j;
                outv[j] = qrow[64 + jj] * sn[jj] + qrow[96 + jj] * cs[jj];
            }
        }
        half8 hv, lv;
#pragma unroll
        for (int j = 0; j < 8; ++j) {
            float o = outv[j] * qscale;
            half_t h = (half_t)o;
            hv[j] = h;
            lv[j] = (half_t)((o - (float)h) * 1024.0f);
        }
        size_t base = (size_t)t * (NH * HD) + hh * HD + d0;
        *(half8*)(qh + base) = hv;
        *(half8*)(ql + base) = lv;
    }
    {
        const float* krow = row + NH * HD + wid * HD;
        float a0 = krow[lane], a1 = krow[64 + lane];
        float ss = a0 * a0 + a1 * a1;
        for (int o = 32; o; o >>= 1) ss += __shfl_down(ss, o);
        ss = __shfl(ss, 0);
        float rs = rsqrtf(ss * (1.0f / HD) + 1e-6f);
        float n0 = a0 * rs * klnw[lane];
        float n1 = a1 * rs * klnw[64 + lane];
        float other = __shfl_xor(n1, 32);
        int j = lane & 31;
        float o1 = (lane < 32) ? (n1 * cs[j] - other * sn[j])
                               : (other * sn[j] + n1 * cs[j]);
        size_t base = (size_t)t * (NKVH * HD) + wid * HD;
        half_t h;
        h = (half_t)n0; kh[base + lane] = h;
        kl[base + lane] = (half_t)((n0 - (float)h) * 1024.0f);
        h = (half_t)o1; kh[base + 64 + lane] = h;
        kl[base + 64 + lane] = (half_t)((o1 - (float)h) * 1024.0f);
    }
}

// ---------------------------------------------------------------------------
// Chunked flash attention, causal GQA, split-f16 MFMA. Chunks balanced
// evenly within each q (tiles [c*nt/nch, (c+1)*nt/nch)).
// ---------------------------------------------------------------------------
__global__ __launch_bounds__(256, 2)
void attn_kernel(const half_t* __restrict__ qh, const half_t* __restrict__ ql,
                 const half_t* __restrict__ kh, const half_t* __restrict__ kl,
                 const half_t* __restrict__ vth, const half_t* __restrict__ vtl,
                 half_t* __restrict__ oh, half_t* __restrict__ ol,
                 float* __restrict__ Op0, float* __restrict__ Op1,
                 float* __restrict__ ml)
{
    const int bid = blockIdx.x;
    const int h = bid & 15, r = bid >> 4;
    int q, c;
    if (r < 8)       { q = r;                 c = 0; }
    else if (r < 24) { q = 8 + ((r - 8) >> 1);  c = (r - 8) & 1; }
    else if (r < 48) { q = 16 + (r - 24) / 3;   c = (r - 24) % 3; }
    else             { q = 24 + ((r - 48) >> 2); c = (r - 48) & 3; }
    const int nch = (q < 8) ? 1 : (q < 16) ? 2 : (q < 24) ? 3 : 4;
    const int nt = 2 * (q + 1);                    // 32-wide kv tiles
    const int kvbeg = ((c * nt) / nch) * 32;
    const int kvend = (((c + 1) * nt) / nch) * 32;

    const int kvh = h >> 2;
    const int tid = threadIdx.x, lane = tid & 63, wid = tid >> 6;
    const int q0 = q * 64 + wid * 16;
    const int l15 = lane & 15, l4 = lane >> 4;

    __shared__ half_t Ksh[32][136], Ksl[32][136];
    __shared__ half_t Vsh[128][40], Vsl[128][40];
    __shared__ half_t Ph[4][16][40], Pl[4][16][40];

    half8 qfh[4], qfl[4];
    {
        const size_t qb = (size_t)(q0 + l15) * (NH * HD) + h * HD + l4 * 8;
#pragma unroll
        for (int cc = 0; cc < 4; ++cc) {
            qfh[cc] = *(const half8*)(qh + qb + cc * 32);
            qfl[cc] = *(const half8*)(ql + qb + cc * 32);
        }
    }

    f32x4 om[8] = {}, oc[8] = {};
    float mrow[4] = { -1e30f, -1e30f, -1e30f, -1e30f };
    float lrow[4] = {};

    const int kr = tid >> 4, kc = (tid & 15) * 8;
    const int vd = tid >> 2, vc = (tid & 3) * 8;
    uint4 rk0h, rk1h, rk0l, rk1l, rv0h, rv1h, rv0l, rv1l;  // NAMED (rule #20)

#define LOAD_TILE(KV0)                                                        \
    do {                                                                      \
        size_t sk0 = (size_t)((KV0) + kr) * (NKVH * HD) + kvh * HD + kc;      \
        size_t sk1 = sk0 + (size_t)16 * (NKVH * HD);                          \
        rk0h = *(const uint4*)(kh + sk0);  rk0l = *(const uint4*)(kl + sk0);  \
        rk1h = *(const uint4*)(kh + sk1);  rk1l = *(const uint4*)(kl + sk1);  \
        size_t sv0 = (size_t)(kvh * HD + vd) * T_TOK + (KV0) + vc;            \
        size_t sv1 = sv0 + (size_t)64 * T_TOK;                                \
        rv0h = *(const uint4*)(vth + sv0); rv0l = *(const uint4*)(vtl + sv0); \
        rv1h = *(const uint4*)(vth + sv1); rv1l = *(const uint4*)(vtl + sv1); \
    } while (0)

    LOAD_TILE(kvbeg);
    for (int kv0 = kvbeg; kv0 < kvend; kv0 += 32) {
        *(uint4*)&Ksh[kr][kc]      = rk0h;  *(uint4*)&Ksl[kr][kc]      = rk0l;
        *(uint4*)&Ksh[kr + 16][kc] = rk1h;  *(uint4*)&Ksl[kr + 16][kc] = rk1l;
        *(uint4*)&Vsh[vd][vc]      = rv0h;  *(uint4*)&Vsl[vd][vc]      = rv0l;
        *(uint4*)&Vsh[vd + 64][vc] = rv1h;  *(uint4*)&Vsl[vd + 64][vc] = rv1l;
        __syncthreads();
        if (kv0 + 32 < kvend) LOAD_TILE(kv0 + 32);

        f32x4 sf[2];
        __builtin_amdgcn_s_setprio(1);
#pragma unroll
        for (int t2 = 0; t2 < 2; ++t2) {
            f32x4 s = {}, sc = {};
#pragma unroll
            for (int cc = 0; cc < 4; ++cc) {
                half8 bh = *(const half8*)&Ksh[t2 * 16 + l15][cc * 32 + l4 * 8];
                half8 bl = *(const half8*)&Ksl[t2 * 16 + l15][cc * 32 + l4 * 8];
                s  = MFMA16(qfh[cc], bh, s);
                sc = MFMA16(qfh[cc], bl, sc);
                sc = MFMA16(qfl[cc], bh, sc);
            }
            sf[t2] = s + sc * (1.0f / 1024.0f);
        }
        __builtin_amdgcn_s_setprio(0);

        float pmax[4];
#pragma unroll
        for (int i = 0; i < 4; ++i) {
            const int qg = q0 + l4 * 4 + i;
#pragma unroll
            for (int t2 = 0; t2 < 2; ++t2) {
                int kvg = kv0 + t2 * 16 + l15;
                if (kvg > qg) sf[t2][i] = -1e30f;
            }
            float mx = fmaxf(sf[0][i], sf[1][i]);
#pragma unroll
            for (int o = 1; o < 16; o <<= 1) mx = fmaxf(mx, __shfl_xor(mx, o));
            pmax[i] = mx;
        }
        float dm = fmaxf(fmaxf(pmax[0] - mrow[0], pmax[1] - mrow[1]),
                         fmaxf(pmax[2] - mrow[2], pmax[3] - mrow[3]));
        if (__any(dm > 6.0f)) {
#pragma unroll
            for (int i = 0; i < 4; ++i) {
                float mnew = fmaxf(mrow[i], pmax[i]);
                float resc = expf(mrow[i] - mnew);
                lrow[i] *= resc;
#pragma unroll
                for (int c8 = 0; c8 < 8; ++c8) {
                    om[c8][i] *= resc; oc[c8][i] *= resc;
                }
                mrow[i] = mnew;
            }
        }
#pragma unroll
        for (int i = 0; i < 4; ++i) {
            float p0 = expf(sf[0][i] - mrow[i]);
            float p1 = expf(sf[1][i] - mrow[i]);
            lrow[i] += p0 + p1;
            half_t hh;
            hh = (half_t)p0;
            Ph[wid][l4 * 4 + i][l15] = hh;
            Pl[wid][l4 * 4 + i][l15] = (half_t)((p0 - (float)hh) * 1024.0f);
            hh = (half_t)p1;
            Ph[wid][l4 * 4 + i][16 + l15] = hh;
            Pl[wid][l4 * 4 + i][16 + l15] = (half_t)((p1 - (float)hh) * 1024.0f);
        }

        half8 pah = *(const half8*)&Ph[wid][l15][l4 * 8];
        half8 pal = *(const half8*)&Pl[wid][l15][l4 * 8];
        __builtin_amdgcn_s_setprio(1);
#pragma unroll
        for (int c8 = 0; c8 < 8; ++c8) {
            half8 vh = *(const half8*)&Vsh[c8 * 16 + l15][l4 * 8];
            half8 vl = *(const half8*)&Vsl[c8 * 16 + l15][l4 * 8];
            om[c8] = MFMA16(pah, vh, om[c8]);
            oc[c8] = MFMA16(pah, vl, oc[c8]);
            oc[c8] = MFMA16(pal, vh, oc[c8]);
        }
        __builtin_amdgcn_s_setprio(0);
        __syncthreads();
    }
#undef LOAD_TILE

#pragma unroll
    for (int i = 0; i < 4; ++i)
#pragma unroll
        for (int o = 1; o < 16; o <<= 1) lrow[i] += __shfl_xor(lrow[i], o);

    if (nch == 1) {
#pragma unroll
        for (int c8 = 0; c8 < 8; ++c8) {
#pragma unroll
            for (int i = 0; i < 4; ++i) {
                float v = (om[c8][i] + oc[c8][i] * (1.0f / 1024.0f)) / lrow[i];
                size_t idx = (size_t)(q0 + l4 * 4 + i) * (NH * HD) + h * HD
                           + c8 * 16 + l15;
                half_t hh = (half_t)v;
                oh[idx] = hh;
                ol[idx] = (half_t)((v - (float)hh) * 1024.0f);
            }
        }
    } else {
        float* Op = (bid < 768) ? Op0 + (size_t)bid * 8192
                                : Op1 + (size_t)(bid - 768) * 8192;
#pragma unroll
        for (int c8 = 0; c8 < 8; ++c8) {
#pragma unroll
            for (int i = 0; i < 4; ++i) {
                int row64 = wid * 16 + l4 * 4 + i;
                Op[row64 * 128 + c8 * 16 + l15] =
                    om[c8][i] + oc[c8][i] * (1.0f / 1024.0f);
            }
        }
        if (l15 == 0) {
#pragma unroll
            for (int i = 0; i < 4; ++i) {
                int row64 = wid * 16 + l4 * 4 + i;
                ml[(size_t)bid * 128 + row64]      = mrow[i];
                ml[(size_t)bid * 128 + 64 + row64] = lrow[i];
            }
        }
    }
}

// ---------------------------------------------------------------------------
// Combine partial attention chunks (q >= 8). Grid 384 blocks.
// ---------------------------------------------------------------------------
__global__ __launch_bounds__(256)
void attn_combine(const float* __restrict__ Op0, const float* __restrict__ Op1,
                  const float* __restrict__ ml,
                  half_t* __restrict__ oh, half_t* __restrict__ ol)
{
    const int bid = blockIdx.x;
    const int h = bid & 15, q = 8 + (bid >> 4);
    const int nch = (q < 16) ? 2 : (q < 24) ? 3 : 4;
    const int r0 = (q < 16) ? 8 + (q - 8) * 2
                 : (q < 24) ? 24 + (q - 16) * 3
                            : 48 + (q - 24) * 4;
    const int tid = threadIdx.x;
    const int row = tid >> 2, cg = (tid & 3) * 32;

    const float* Oc[4];
    float m[4], lv[4];
#pragma unroll
    for (int c = 0; c < 4; ++c) {
        int cc = (c < nch) ? c : nch - 1;
        int slot = (r0 + cc) * 16 + h;
        const float* base = (slot < 768) ? Op0 + (size_t)slot * 8192
                                         : Op1 + (size_t)(slot - 768) * 8192;
        Oc[c] = base + row * 128 + cg;
        m[c]  = ml[(size_t)slot * 128 + row];
        lv[c] = (c < nch) ? ml[(size_t)slot * 128 + 64 + row] : 0.0f;
    }
    float M = fmaxf(fmaxf(m[0], m[1]), fmaxf(m[2], m[3]));
    float w[4], wsum = 0.0f;
#pragma unroll
    for (int c = 0; c < 4; ++c) { w[c] = expf(m[c] - M); wsum += lv[c] * w[c]; }
    float inv = 1.0f / wsum;
    float wO[4];
#pragma unroll
    for (int c = 0; c < 4; ++c) wO[c] = (c < nch) ? w[c] * inv : 0.0f;

    size_t obase = (size_t)(q * 64 + row) * (NH * HD) + h * HD + cg;
#pragma unroll
    for (int jj = 0; jj < 4; ++jj) {
        floatx4 a0 = {0,0,0,0}, a1 = {0,0,0,0};
#pragma unroll
        for (int c = 0; c < 4; ++c) {
            floatx4 v0 = *(const floatx4*)(Oc[c] + jj * 8);
            floatx4 v1 = *(const floatx4*)(Oc[c] + jj * 8 + 4);
            a0 += wO[c] * v0;
            a1 += wO[c] * v1;
        }
        half8 hv, lvv;
#pragma unroll
        for (int k = 0; k < 4; ++k) {
            half_t hh = (half_t)a0[k];
            hv[k] = hh; lvv[k] = (half_t)((a0[k] - (float)hh) * 1024.0f);
            hh = (half_t)a1[k];
            hv[4 + k] = hh; lvv[4 + k] = (half_t)((a1[k] - (float)hh) * 1024.0f);
        }
        *(half8*)(oh + obase + jj * 8) = hv;
        *(half8*)(ol + obase + jj * 8) = lvv;
    }
}

// ---------------------------------------------------------------------------
// Linear router: logit_e = rs(x2)*(x.u_e + attn.ow_u_e). Writes top-2 idx,
// normalized weights, and histograms expert counts (cnt pre-zeroed).
// ---------------------------------------------------------------------------
__global__ __launch_bounds__(256)
void router_linear(const float* __restrict__ x, const half_t* __restrict__ ah,
                   const half_t* __restrict__ al, const float* __restrict__ x2,
                   const float* __restrict__ ln2w, const float* __restrict__ rw,
                   const float* __restrict__ owu,
                   int* __restrict__ topi, float* __restrict__ topv,
                   int* __restrict__ cnt)
{
    const int t = blockIdx.x, tid = threadIdx.x;
    const float* xr2 = x2 + (size_t)t * HIDN;
    float ss = 0.0f;
#pragma unroll
    for (int i = 0; i < 8; ++i) {
        float v = xr2[tid + i * 256];
        ss += v * v;
    }
    for (int o = 32; o; o >>= 1) ss += __shfl_down(ss, o);
    __shared__ float red[4];
    if ((tid & 63) == 0) red[tid >> 6] = ss;
    __syncthreads();
    ss = red[0] + red[1] + red[2] + red[3];
    float rs = rsqrtf(ss * (1.0f / HIDN) + 1e-6f);

    const float* xr = x + (size_t)t * HIDN;
    const half_t* ar = ah + (size_t)t * HIDN;
    const half_t* alr = al + (size_t)t * HIDN;
    float acc[NEXP] = {};
#pragma unroll
    for (int i = 0; i < 8; ++i) {
        int c = tid + i * 256;
        float xv = xr[c] * ln2w[c];
        float ap = (float)ar[c] + (float)alr[c] * (1.0f / 1024.0f);
        const float* rwc = rw + (size_t)c * NEXP;
        const float* owc = owu + (size_t)c * NEXP;
#pragma unroll
        for (int e = 0; e < NEXP; ++e) acc[e] += xv * rwc[e] + ap * owc[e];
    }
#pragma unroll
    for (int e = 0; e < NEXP; ++e)
        for (int o = 32; o; o >>= 1) acc[e] += __shfl_down(acc[e], o);
    __shared__ float red8[4][NEXP];
    if ((tid & 63) == 0)
#pragma unroll
        for (int e = 0; e < NEXP; ++e) red8[tid >> 6][e] = acc[e];
    __syncthreads();
    if (tid == 0) {
        float lg[NEXP];
#pragma unroll
        for (int e = 0; e < NEXP; ++e)
            lg[e] = (red8[0][e] + red8[1][e] + red8[2][e] + red8[3][e]) * rs;
        int i1 = 0;
        for (int e = 1; e < NEXP; ++e) if (lg[e] > lg[i1]) i1 = e;
        int i2 = (i1 == 0) ? 1 : 0;
        for (int e = 0; e < NEXP; ++e) if (e != i1 && lg[e] > lg[i2]) i2 = e;
        float mx = lg[i1];
        float p1 = expf(lg[i1] - mx), p2 = expf(lg[i2] - mx);
        float inv = 1.0f / (p1 + p2);
        topi[2 * t] = i1;     topi[2 * t + 1] = i2;
        topv[2 * t] = p1 * inv; topv[2 * t + 1] = p2 * inv;
        atomicAdd(&cnt[i1], 1);
        atomicAdd(&cnt[i2], 1);
    }
}

// ---------------------------------------------------------------------------
// MoE bookkeeping kernels
// ---------------------------------------------------------------------------
__global__ __launch_bounds__(256)
void moe_init(int* __restrict__ cnt, int* __restrict__ pairTok,
              float* __restrict__ pairW)
{
    int idx = blockIdx.x * 256 + threadIdx.x;
    if (idx < NPAIR_MAX) { pairTok[idx] = 0; pairW[idx] = 0.0f; }
    if (idx < NEXP) cnt[idx] = 0;
}

__global__ __launch_bounds__(64)
void moe_scan(const int* __restrict__ cnt, int* __restrict__ fill,
              int* __restrict__ basep)
{
    if (threadIdx.x == 0) {
        int acc = 0;
        for (int e = 0; e < NEXP; ++e) {
            basep[e] = acc;
            fill[e] = acc;
            acc += (cnt[e] + 63) & ~63;
        }
        basep[NEXP] = acc;
    }
}

__global__ __launch_bounds__(256)
void moe_scatter(const int* __restrict__ topi, const float* __restrict__ topv,
                 int* __restrict__ fill, int* __restrict__ pairTok,
                 float* __restrict__ pairW, int* __restrict__ pairPos)
{
    int t = blockIdx.x * 256 + threadIdx.x;
#pragma unroll
    for (int j = 0; j < 2; ++j) {
        int e = topi[2 * t + j];
        int pos = atomicAdd(&fill[e], 1);
        pairTok[pos] = t;
        pairW[pos] = topv[2 * t + j];
        pairPos[2 * t + j] = pos;
    }
}

// ---------------------------------------------------------------------------
// Activations: shared (GUs[2048][2048]: gate|up) and sparse (GUp[p][1024]).
// ---------------------------------------------------------------------------
__global__ __launch_bounds__(256)
void act_shared(const half_t* __restrict__ GUs, half_t* __restrict__ As)
{
    int idx = blockIdx.x * 256 + threadIdx.x;   // 2048*128 threads
    int t = idx >> 7, c = (idx & 127) * 8;
    half8 g8 = *(const half8*)(GUs + (size_t)t * 2048 + c);
    half8 u8 = *(const half8*)(GUs + (size_t)t * 2048 + 1024 + c);
    half8 o8;
#pragma unroll
    for (int j = 0; j < 8; ++j)
        o8[j] = (half_t)(silu_f((float)g8[j]) * (float)u8[j]);
    *(half8*)(As + (size_t)t * 1024 + c) = o8;
}

__global__ __launch_bounds__(256)
void act_sparse(const half_t* __restrict__ GUp, const float* __restrict__ pairW,
                half_t* __restrict__ Ab)
{
    int idx = blockIdx.x * 256 + threadIdx.x;   // 4608*64 threads
    int p = idx >> 6, c = (idx & 63) * 8;
    half8 g8 = *(const half8*)(GUp + (size_t)p * 1024 + c);
    half8 u8 = *(const half8*)(GUp + (size_t)p * 1024 + 512 + c);
    float w = pairW[p];
    half8 o8;
#pragma unroll
    for (int j = 0; j < 8; ++j)
        o8[j] = (half_t)(silu_f((float)g8[j]) * (float)u8[j] * w);
    *(half8*)(Ab + (size_t)p * 512 + c) = o8;
}

// ---------------------------------------------------------------------------
// Final: out[t] += Ypair[p1] + Ypair[p2]  (out already = x2 + sharedDown)
// ---------------------------------------------------------------------------
__global__ __launch_bounds__(256)
void moe_final(const half_t* __restrict__ Ypair, const int* __restrict__ pairPos,
               float* __restrict__ out)
{
    int t = blockIdx.x, c0 = threadIdx.x * 8;
    int p1 = pairPos[2 * t], p2 = pairPos[2 * t + 1];
    half8 y1 = *(const half8*)(Ypair + (size_t)p1 * HIDN + c0);
    half8 y2 = *(const half8*)(Ypair + (size_t)p2 * HIDN + c0);
    float* o = out + (size_t)t * HIDN + c0;
    floatx4 a = *(floatx4*)o, b = *(floatx4*)(o + 4);
#pragma unroll
    for (int j = 0; j < 4; ++j) {
        a[j] += (float)y1[j] + (float)y2[j];
        b[j] += (float)y1[4 + j] + (float)y2[4 + j];
    }
    *(floatx4*)o = a;
    *(floatx4*)(o + 4) = b;
}

// ---------------------------------------------------------------------------
extern "C" void kernel_launch(void* const* d_in, const int* in_sizes, int n_in,
                              void* d_out, int out_size, void* d_ws, size_t ws_size,
                              hipStream_t stream)
{
    (void)in_sizes; (void)n_in; (void)out_size; (void)ws_size;
    const float* x    = (const float*)d_in[0];
    const int*   pos  = (const int*)  d_in[1];
    const float* ln1w = (const float*)d_in[2];
    const float* qkvw = (const float*)d_in[3];
    const float* qkvb = (const float*)d_in[4];
    const float* klnw = (const float*)d_in[5];
    const float* ow   = (const float*)d_in[6];
    const float* ln2w = (const float*)d_in[7];
    const float* rw   = (const float*)d_in[8];
    const float* w1   = (const float*)d_in[9];
    const float* w2   = (const float*)d_in[10];
    const float* w3   = (const float*)d_in[11];
    const float* sw1  = (const float*)d_in[12];
    const float* sw2  = (const float*)d_in[13];
    const float* sw3  = (const float*)d_in[14];
    float* out = (float*)d_out;

    // ---- workspace arena (phase-overlapped; total 142,671,872 B) ----
    char* ws = (char*)d_ws;
    const size_t AB = 16842752;
    float*  x2      = (float*)(ws);                   // also Opart1
    half_t* h_hi    = (half_t*)(ws + AB);
    half_t* h_lo    = (half_t*)(ws + AB + 8388608);
    half_t* qkvwt_h = (half_t*)(ws + AB + 16777216);
    half_t* qkvwt_l = (half_t*)(ws + AB + 29360128);
    float*  qkv     = (float*)(ws + AB + 41943040);   // also Opart0 / W13t
    half_t* q_h     = (half_t*)(ws + AB + 67108864);
    half_t* q_l     = (half_t*)(ws + AB + 75497472);
    half_t* k_h     = (half_t*)(ws + AB + 83886080);
    half_t* k_l     = (half_t*)(ws + AB + 85983232);
    half_t* vt_h    = (half_t*)(ws + AB + 88080384);
    half_t* vt_l    = (half_t*)(ws + AB + 90177536);
    half_t* attn_h  = (half_t*)(ws + AB);             // reuse h_hi
    half_t* attn_l  = (half_t*)(ws + AB + 8388608);   // reuse h_lo
    half_t* owt     = (half_t*)(ws + AB + 16777216);  // reuse qkvwt_h
    float*  ow_u    = (float*)(ws + AB + 25165824);   // 64 KB
    // meta (old mlpart region, dead after attn_combine):
    int*    cnt     = (int*)(ws + AB + 25231360);
    int*    fill    = cnt + 16;
    int*    basep   = cnt + 32;
    int*    topi    = cnt + 64;                       // 4096 ints
    float*  topv    = (float*)(cnt + 4160);           // 4096 floats
    int*    pairPos = (int*)(cnt + 8256);             // 4096 ints
    int*    pairTok = (int*)(cnt + 12352);            // 4608 ints
    float*  pairW   = (float*)(cnt + 16960);          // 4608 floats
    float*  mlpart  = (float*)(ws + AB + 25231360);   // attn partial m/l (pre-MoE)
    float*  Opart0  = (float*)(ws + AB + 41943040);   // = qkv region
    float*  Opart1  = (float*)(ws);                   // = x2 region
    half_t* h2      = (half_t*)(ws + AB + 33554432);  // 8.4MB
    half_t* W13t    = (half_t*)(ws + AB + 41943040);  // 41.9MB (qkv+q dead)
    half_t* GUs     = (half_t*)(ws + AB + 83886080);  // 8.4MB (k/v dead)
    half_t* As_sh   = (half_t*)(ws + AB);             // 4.2MB (attn dead post-router)
    half_t* GUp     = (half_t*)(ws + AB + 4194304);   // 9.4MB
    half_t* Ab      = (half_t*)(ws + AB + 16777216);  // 4.7MB (owt dead)
    half_t* W2t     = (half_t*)(ws + AB + 41943040);  // 21MB (W13t dead post-GU)
    half_t* Ypair   = (half_t*)(ws + AB + 92274688);  // 18.9MB

    dim3 b256(256);

    // 1. h = rmsnorm(x, ln1_w) split
    rmsnorm_split_k<<<T_TOK, b256, 0, stream>>>(x, ln1w, h_hi, h_lo);
    // 2. qkv_w -> transposed split f16
    transpose_split2<<<dim3(QKV_N / 32, HIDN / 32), b256, 0, stream>>>(
        qkvw, qkvwt_h, qkvwt_l, QKV_N, HIDN);
    // 3. qkv = h @ qkv_w + b   (split path)
    gemm_f16<true, 64><<<dim3(QKV_N / 128, T_TOK / 64), b256, 0, stream>>>(
        h_hi, h_lo, qkvwt_h, qkvwt_l, qkvb, nullptr, qkv, nullptr,
        T_TOK, QKV_N, HIDN, HIDN);
    // 4. k-rmsnorm + rope + split (q pre-scaled)
    qkv_prep<<<T_TOK, b256, 0, stream>>>(qkv, pos, klnw, q_h, q_l, k_h, k_l);
    // 5. v^T (split)
    transpose_split2<<<dim3(512 / 32, T_TOK / 32), b256, 0, stream>>>(
        qkv + 2560, vt_h, vt_l, QKV_N, T_TOK);
    // 6. o_w transpose (single f16)
    transpose_f16<<<dim3(HIDN / 64, HIDN / 32), b256, 0, stream>>>(
        ow, owt, HIDN, HIDN);
    // 7. ow_u = o_w @ (ln2w * rw)
    owu_kernel<<<512, b256, 0, stream>>>(ow, ln2w, rw, ow_u);
    // 8. attention (chunked KV, balanced boundaries)
    attn_kernel<<<1280, b256, 0, stream>>>(
        q_h, q_l, k_h, k_l, vt_h, vt_l, attn_h, attn_l,
        Opart0, Opart1, mlpart);
    // 8b. combine partial chunks
    attn_combine<<<384, b256, 0, stream>>>(Opart0, Opart1, mlpart,
                                           attn_h, attn_l);
    // 9. x2 = x + attn @ o_w   (single f16)
    gemm_f16<false, 64><<<dim3(HIDN / 128, T_TOK / 64), b256, 0, stream>>>(
        attn_h, nullptr, owt, nullptr, nullptr, x, x2, nullptr,
        T_TOK, HIDN, HIDN, HIDN);
    // 9b. MoE meta init (after attn_combine freed mlpart region)
    moe_init<<<18, b256, 0, stream>>>(cnt, pairTok, pairW);
    // 10. router -> top-2 idx/weights + expert histogram
    router_linear<<<T_TOK, b256, 0, stream>>>(
        x, attn_h, attn_l, x2, ln2w, rw, ow_u, topi, topv, cnt);
    // 10b. 64-aligned exclusive scan
    moe_scan<<<1, 64, 0, stream>>>(cnt, fill, basep);
    // 10c. scatter pairs
    moe_scatter<<<NEXP, b256, 0, stream>>>(topi, topv, fill,
                                           pairTok, pairW, pairPos);
    // 11. h2 = rmsnorm(x2, ln2_w), single f16
    rmsnorm_split_k<<<T_TOK, b256, 0, stream>>>(x2, ln2w, h2, nullptr);
    // 12. W13t batched transpose (new layout)
    w13_transpose<<<dim3(10240 / 64, HIDN / 32), b256, 0, stream>>>(
        sw1, w1, sw3, w3, W13t);
    // 13. shared GU: GUs = h2 @ [sw1|sw3]  (N=2048, contiguous B rows 0-2047)
    gemm_f16<false, 64><<<dim3(2048 / 128, T_TOK / 64), b256, 0, stream>>>(
        h2, nullptr, W13t, nullptr, nullptr, nullptr, nullptr, GUs,
        T_TOK, 2048, HIDN, HIDN);
    // 14. grouped GU (experts, gathered A rows)
    gemm_grouped_gu<<<dim3(8, NPAIR_MAX / 64), b256, 0, stream>>>(
        h2, W13t, pairTok, basep, GUp);
    // 15. activations
    act_shared<<<(T_TOK * 128) / 256, b256, 0, stream>>>(GUs, As_sh);
    act_sparse<<<(NPAIR_MAX * 64) / 256, b256, 0, stream>>>(GUp, pairW, Ab);
    // 16. W2t batched transpose (overwrites dead W13t)
    w2_transpose<<<dim3(HIDN / 64, 5120 / 32), b256, 0, stream>>>(sw2, w2, W2t);
    // 17. shared down: out = x2 + As_sh @ sw2^T  (K=1024, ldb=5120)
    gemm_f16<false, 64><<<dim3(HIDN / 128, T_TOK / 64), b256, 0, stream>>>(
        As_sh, nullptr, W2t, nullptr, nullptr, x2, out, nullptr,
        T_TOK, HIDN, 1024, 5120);
    // 18. grouped down (experts) -> Ypair
    gemm_grouped_down<<<dim3(16, NPAIR_MAX / 64), b256, 0, stream>>>(
        Ab, W2t, basep, Ypair);
    // 19. out += Ypair[p1] + Ypair[p2]
    moe_final<<<T_TOK, b256, 0, stream>>>(Ypair, pairPos, out);
}